// Round 14
// baseline (348.861 us; speedup 1.0000x reference)
//
#include <hip/hip_runtime.h>
#include <hip/hip_bf16.h>
#include <stdint.h>

#define IN_DIM 384
#define HID 64
#define C1 256   // 4 heads * 64
#define C2 128   // 2 heads * 64

typedef unsigned int uint32;
typedef __bf16 bf16x8 __attribute__((ext_vector_type(8)));
typedef float f32x4 __attribute__((ext_vector_type(4)));

static __device__ __forceinline__ float bf2f(unsigned short u){
    return __uint_as_float(((uint32)u) << 16);
}
static __device__ __forceinline__ unsigned short f2bf(float x){
    uint32 u = __float_as_uint(x);
    return (unsigned short)((u + 0x7FFFu + ((u >> 16) & 1u)) >> 16);
}
static __device__ __forceinline__ uint32 pack2(float a, float b){
    return (uint32)f2bf(a) | ((uint32)f2bf(b) << 16);
}

// ---------------- CSR build ----------------
__global__ void k_zero(int* deg, int* cur, int N){
    int i = blockIdx.x*256 + threadIdx.x;
    if (i < N){ deg[i] = 0; cur[i] = 0; }
}
__global__ void k_hist(const int* __restrict__ ei, int* deg, int E){
    int i = blockIdx.x*256 + threadIdx.x;
    if (i < E) atomicAdd(&deg[ei[E + i]], 1);
}
__global__ void k_scan1(const int* __restrict__ deg, int* rowptr, int* part, int N){
    __shared__ int s[256];
    int tid = threadIdx.x;
    int i = blockIdx.x*256 + tid;
    int v = (i < N) ? deg[i] : 0;
    s[tid] = v; __syncthreads();
    for (int off = 1; off < 256; off <<= 1){
        int t = (tid >= off) ? s[tid - off] : 0;
        __syncthreads();
        s[tid] += t;
        __syncthreads();
    }
    if (i < N) rowptr[i] = s[tid] - v;
    if (tid == 255) part[blockIdx.x] = s[tid];
}
__global__ void k_scan2(int* part, int nb){
    __shared__ int s[512];
    int tid = threadIdx.x;
    int v = (tid < nb) ? part[tid] : 0;
    s[tid] = v; __syncthreads();
    for (int off = 1; off < 512; off <<= 1){
        int t = (tid >= off) ? s[tid - off] : 0;
        __syncthreads();
        s[tid] += t;
        __syncthreads();
    }
    if (tid < nb) part[tid] = s[tid] - v;
}
__global__ void k_scan3(int* rowptr, const int* __restrict__ part, int N, int E){
    int i = blockIdx.x*256 + threadIdx.x;
    if (i < N) rowptr[i] += part[blockIdx.x];
    if (i == 0) rowptr[N] = E;
}
__global__ void k_scatter(const int* __restrict__ ei, const int* __restrict__ rowptr,
                          int* cur, int* colx, int* dstx, int E){
    int i = blockIdx.x*256 + threadIdx.x;
    if (i < E){
        int d = ei[E + i];
        int pos = atomicAdd(&cur[d], 1);
        int p = rowptr[d] + pos;
        colx[p] = ei[i];
        dstx[p] = d;
    }
}

// ---------------- weight pre-swizzle: contiguous-k fragment order ----------------
// Wf[unit = ku*ntiles+ct][lane l][j] = W[k = ku*32 + 8*(l>>4) + j][ct*16 + (l&15)]
__global__ __launch_bounds__(256) void k_cvtW(const float* __restrict__ W,
        unsigned short* __restrict__ Wf, int ncol, int ntiles, int nunits){
    int unit = blockIdx.x*4 + (threadIdx.x >> 6);
    if (unit >= nunits) return;
    int l = threadIdx.x & 63;
    int s = unit / ntiles, ct = unit % ntiles;
    int col = ct*16 + (l & 15);
    int g = l >> 4;
    unsigned short o[8];
    #pragma unroll
    for (int j = 0; j < 8; j++){
        int k = s*32 + g*8 + j;
        o[j] = f2bf(W[(size_t)k*ncol + col]);
    }
    ushort4* dst = (ushort4*)&Wf[((size_t)unit*64 + l)*8];
    dst[0] = make_ushort4(o[0], o[1], o[2], o[3]);
    dst[1] = make_ushort4(o[4], o[5], o[6], o[7]);
}

// ---------------- x fp32 -> bf16 pre-swizzle, SEQUENTIAL READ version ----------------
// Thread t reads float4 index flat = it*256+t of the block's 96KB row-range:
// per-wave 1KB contiguous, per-block one sequential 96KB stream (HBM-friendly).
// The fragment-order swizzle happens on the WRITE side (8B stores into the
// block's 48KB chunk — L2-absorbed). Chunk layout matches k_gemm1's linear read:
// chunk c = (ku*4+rt)*64+lane holds x[n0+rt*16+(lane&15)][ku*32+(lane>>4)*8 ..+8].
__global__ __launch_bounds__(256) void k_cvtX(const float* __restrict__ x,
        unsigned short* __restrict__ xs, int N){
    const int blk = blockIdx.x;
    const int n0  = blk*64;
    const int t   = threadIdx.x;
    unsigned short* dst = xs + (size_t)blk*24576;   // 64*384 bf16 per block
    const bool full = (n0 + 64 <= N);
    #pragma unroll
    for (int it = 0; it < 24; ++it){
        int flat = it*256 + t;          // float4 index in [0, 6144)
        int row  = flat / 96;           // 0..63
        int k4   = flat - row*96;       // 0..95
        int k    = k4*4;
        const float* src;
        if (full){
            src = x + (size_t)n0*IN_DIM + (size_t)flat*4;   // fully sequential
        } else {
            int n = n0 + row; if (n > N-1) n = N-1;
            src = x + (size_t)n*IN_DIM + k;
        }
        float4 a = *(const float4*)src;
        int ku   = k >> 5;
        int l16  = (k >> 3) & 3;
        int half = (k >> 2) & 1;
        int lane = l16*16 + (row & 15);
        int rt   = row >> 4;
        int chunk = (ku*4 + rt)*64 + lane;
        *(uint2*)(dst + (size_t)chunk*8 + half*4) = make_uint2(pack2(a.x, a.y), pack2(a.z, a.w));
    }
}

// ---------------- constant precompute: pad bias, emotion gate ----------
__global__ __launch_bounds__(256) void k_prep(const float* __restrict__ W1,
        const float* __restrict__ pad, const float* __restrict__ gw, const float* __restrict__ gb,
        float* __restrict__ c1v, float* __restrict__ gate){
    int tid = threadIdx.x;
    c1v[tid] = pad[0]*W1[(size_t)(IN_DIM+0)*C1 + tid]
             + pad[1]*W1[(size_t)(IN_DIM+1)*C1 + tid]
             + pad[2]*W1[(size_t)(IN_DIM+2)*C1 + tid];
    if (tid < HID){
        float g = pad[0]*gw[0*HID + tid] + pad[1]*gw[1*HID + tid] + pad[2]*gw[2*HID + tid] + gb[tid];
        gate[tid] = 1.f/(1.f + __expf(-g));
    }
}

// ---------------- GEMM1 (MFMA): h1 = [x|pad]@W1 + fused al1 epilogue ----------------
// Pre-swizzled bf16 input (xs, L3-hot): LDS staging is a LINEAR 48KB memcpy,
// ONE barrier, 12 k-units MFMA. 512 thr / 8 waves: wave = (wr row-half, wc head).
__global__ __launch_bounds__(512) void k_gemm1_mfma(const unsigned short* __restrict__ xs,
        const unsigned short* __restrict__ Wf, const float* __restrict__ c1v,
        const float* __restrict__ as1, const float* __restrict__ ad1,
        unsigned short* __restrict__ h1, float* __restrict__ als, float* __restrict__ ald, int N)
{
    __shared__ unsigned short Af[3072*8];   // 48 KB, fragment order
    const int tid = threadIdx.x;
    const int l   = tid & 63;
    const int w   = tid >> 6;       // 0..7
    const int wr  = w >> 2;         // row half (32 rows)
    const int wc  = w & 3;          // head
    const int n0  = blockIdx.x * 64;

    const unsigned short* src = xs + (size_t)blockIdx.x*24576;
    uint4 st[6];
    #pragma unroll
    for (int j = 0; j < 6; j++) st[j] = *(const uint4*)(src + (size_t)(j*512 + tid)*8);
    #pragma unroll
    for (int j = 0; j < 6; j++) *(uint4*)&Af[(size_t)(j*512 + tid)*8] = st[j];

    f32x4 acc[4][2];
    #pragma unroll
    for (int i = 0; i < 4; i++)
        #pragma unroll
        for (int rt = 0; rt < 2; rt++)
            acc[i][rt] = (f32x4){0.f, 0.f, 0.f, 0.f};

    uint4 wcur[4], wnxt[4];
    {
        const unsigned short* p = Wf + ((size_t)(wc*4)*64 + l)*8;
        #pragma unroll
        for (int i = 0; i < 4; i++) wcur[i] = *(const uint4*)(p + (size_t)i*512);
    }
    __syncthreads();

    for (int ku = 0; ku < 12; ++ku){
        if (ku < 11){
            const unsigned short* p = Wf + ((size_t)((ku+1)*16 + wc*4)*64 + l)*8;
            #pragma unroll
            for (int i = 0; i < 4; i++) wnxt[i] = *(const uint4*)(p + (size_t)i*512);
        }
        bf16x8 af[2];
        #pragma unroll
        for (int rt = 0; rt < 2; rt++)
            af[rt] = __builtin_bit_cast(bf16x8, *(const uint4*)&Af[((ku*4 + wr*2 + rt)*64 + l)*8]);
        #pragma unroll
        for (int i = 0; i < 4; i++){
            bf16x8 bw = __builtin_bit_cast(bf16x8, wcur[i]);
            #pragma unroll
            for (int rt = 0; rt < 2; rt++)
                acc[i][rt] = __builtin_amdgcn_mfma_f32_16x16x32_bf16(bw, af[rt], acc[i][rt], 0, 0, 0);
        }
        if (ku < 11){
            #pragma unroll
            for (int i = 0; i < 4; i++) wcur[i] = wnxt[i];
        }
    }

    const int g = l >> 4;
    float4 cvv[4], av[4], dv[4];
    #pragma unroll
    for (int i = 0; i < 4; i++){
        int cl = i*16 + g*4;
        cvv[i] = *(const float4*)&c1v[wc*64 + cl];
        av[i]  = *(const float4*)&as1[wc*64 + cl];
        dv[i]  = *(const float4*)&ad1[wc*64 + cl];
    }
    #pragma unroll
    for (int rt = 0; rt < 2; rt++){
        int node = n0 + (wr*2 + rt)*16 + (l & 15);
        bool ok = node < N;
        float ps = 0.f, pd = 0.f;
        #pragma unroll
        for (int i = 0; i < 4; i++){
            float h0 = acc[i][rt][0] + cvv[i].x;
            float h1v = acc[i][rt][1] + cvv[i].y;
            float h2v = acc[i][rt][2] + cvv[i].z;
            float h3v = acc[i][rt][3] + cvv[i].w;
            ps += h0*av[i].x + h1v*av[i].y + h2v*av[i].z + h3v*av[i].w;
            pd += h0*dv[i].x + h1v*dv[i].y + h2v*dv[i].z + h3v*dv[i].w;
            if (ok){
                ushort4 o = make_ushort4(f2bf(h0), f2bf(h1v), f2bf(h2v), f2bf(h3v));
                *(ushort4*)&h1[(size_t)node*C1 + wc*64 + i*16 + g*4] = o;
            }
        }
        ps += __shfl_xor(ps, 16, 64); ps += __shfl_xor(ps, 32, 64);
        pd += __shfl_xor(pd, 16, 64); pd += __shfl_xor(pd, 32, 64);
        if (ok && g == 0){
            als[(size_t)node*4 + wc] = ps;
            ald[(size_t)node*4 + wc] = pd;
        }
    }
}

// ---------------- GEMM2 (MFMA): h2 = x2 @ W2 + fused al2 epilogue ----------------
__global__ __launch_bounds__(256) void k_gemm2_mfma(const unsigned short* __restrict__ x2,
        const unsigned short* __restrict__ Wf,
        const float* __restrict__ as2, const float* __restrict__ ad2,
        unsigned short* __restrict__ h2, float* __restrict__ als, float* __restrict__ ald, int N)
{
    __shared__ unsigned short Af[2][4*64*8];   // 2 x 4KB
    const int tid = threadIdx.x;
    const int l   = tid & 63;
    const int w   = tid >> 6;
    const int wr  = w >> 1, wc = w & 1;
    const int n0  = blockIdx.x * 64;

    const int sr  = tid >> 2;
    const int kc  = tid & 3;
    const int d0  = ((sr >> 4)*64 + kc*16 + (sr & 15))*8;
    int crow = n0 + sr; if (crow > N-1) crow = N-1;
    const unsigned short* xrow = x2 + (size_t)crow*C1 + kc*8;

    f32x4 acc[4][2];
    #pragma unroll
    for (int i = 0; i < 4; i++)
        #pragma unroll
        for (int rt = 0; rt < 2; rt++)
            acc[i][rt] = (f32x4){0.f, 0.f, 0.f, 0.f};

    uint4 p0, wcur[4], wnxt[4];
    p0 = *(const uint4*)(xrow);
    *(uint4*)&Af[0][d0] = p0;
    {
        const unsigned short* p = Wf + ((size_t)(wc*4)*64 + l)*8;
        #pragma unroll
        for (int i = 0; i < 4; i++) wcur[i] = *(const uint4*)(p + (size_t)i*512);
    }
    __syncthreads();

    for (int s = 0; s < 8; ++s){
        if (s < 7){
            p0 = *(const uint4*)(xrow + (s+1)*32);
            const unsigned short* p = Wf + ((size_t)((s+1)*8 + wc*4)*64 + l)*8;
            #pragma unroll
            for (int i = 0; i < 4; i++) wnxt[i] = *(const uint4*)(p + (size_t)i*512);
        }
        bf16x8 af[2];
        #pragma unroll
        for (int rt = 0; rt < 2; rt++)
            af[rt] = __builtin_bit_cast(bf16x8, *(const uint4*)&Af[s&1][((wr*2 + rt)*64 + l)*8]);
        #pragma unroll
        for (int i = 0; i < 4; i++){
            bf16x8 bw = __builtin_bit_cast(bf16x8, wcur[i]);
            #pragma unroll
            for (int rt = 0; rt < 2; rt++)
                acc[i][rt] = __builtin_amdgcn_mfma_f32_16x16x32_bf16(bw, af[rt], acc[i][rt], 0, 0, 0);
        }
        if (s < 7){
            *(uint4*)&Af[(s+1)&1][d0] = p0;
            __syncthreads();
            #pragma unroll
            for (int i = 0; i < 4; i++) wcur[i] = wnxt[i];
        }
    }

    const int g = l >> 4;
    float4 av[4], dv[4];
    #pragma unroll
    for (int i = 0; i < 4; i++){
        int cl = i*16 + g*4;
        av[i] = *(const float4*)&as2[wc*64 + cl];
        dv[i] = *(const float4*)&ad2[wc*64 + cl];
    }
    #pragma unroll
    for (int rt = 0; rt < 2; rt++){
        int node = n0 + wr*32 + rt*16 + (l & 15);
        bool ok = node < N;
        float ps = 0.f, pd = 0.f;
        #pragma unroll
        for (int i = 0; i < 4; i++){
            float h0 = acc[i][rt][0], h1v = acc[i][rt][1];
            float h2v = acc[i][rt][2], h3v = acc[i][rt][3];
            ps += h0*av[i].x + h1v*av[i].y + h2v*av[i].z + h3v*av[i].w;
            pd += h0*dv[i].x + h1v*dv[i].y + h2v*dv[i].z + h3v*dv[i].w;
            if (ok){
                ushort4 o = make_ushort4(f2bf(h0), f2bf(h1v), f2bf(h2v), f2bf(h3v));
                *(ushort4*)&h2[(size_t)node*C2 + wc*64 + i*16 + g*4] = o;
            }
        }
        ps += __shfl_xor(ps, 16, 64); ps += __shfl_xor(ps, 32, 64);
        pd += __shfl_xor(pd, 16, 64); pd += __shfl_xor(pd, 32, 64);
        if (ok && g == 0){
            als[(size_t)node*2 + wc] = ps;
            ald[(size_t)node*2 + wc] = pd;
        }
    }
}

// ---------------- A: edge-parallel logits e = leaky(als[src]+ald[dst]) ----------------
template<int H>
__global__ __launch_bounds__(256) void k_elogit(const int* __restrict__ colx,
        const int* __restrict__ dstx, const float* __restrict__ als,
        const float* __restrict__ ald, float* __restrict__ ep, int E)
{
    int i = blockIdx.x*256 + threadIdx.x;
    if (i >= E) return;
    int s = colx[i], d = dstx[i];
    if constexpr (H == 4){
        float4 a = *(const float4*)&als[(size_t)s*4];
        float4 b = *(const float4*)&ald[(size_t)d*4];
        float4 e;
        e.x = a.x + b.x; e.x = fmaxf(e.x, 0.2f*e.x);
        e.y = a.y + b.y; e.y = fmaxf(e.y, 0.2f*e.y);
        e.z = a.z + b.z; e.z = fmaxf(e.z, 0.2f*e.z);
        e.w = a.w + b.w; e.w = fmaxf(e.w, 0.2f*e.w);
        *(float4*)&ep[(size_t)i*4] = e;
    } else {
        float2 a = *(const float2*)&als[(size_t)s*2];
        float2 b = *(const float2*)&ald[(size_t)d*2];
        float2 e;
        e.x = a.x + b.x; e.x = fmaxf(e.x, 0.2f*e.x);
        e.y = a.y + b.y; e.y = fmaxf(e.y, 0.2f*e.y);
        *(float2*)&ep[(size_t)i*2] = e;
    }
}

// ---------------- B: thread per (node,head) segment softmax; ep <- p (in place) -------
template<int H>
__global__ __launch_bounds__(256) void k_segsm(const int* __restrict__ rowptr,
        const float* __restrict__ als, const float* __restrict__ ald,
        float* __restrict__ ep, float* __restrict__ den, float* __restrict__ pSelf, int NH)
{
    int t = blockIdx.x*256 + threadIdx.x;
    if (t >= NH) return;
    int node = t / H;
    int head = t - node*H;
    int base = rowptr[node];
    int cnt  = rowptr[node+1] - base;
    float es = als[t] + ald[t];
    es = fmaxf(es, 0.2f*es);
    float m = es;
    for (int j = 0; j < cnt; j++)
        m = fmaxf(m, ep[(size_t)(base + j)*H + head]);
    float ps = __expf(es - m);
    float dn = ps;
    for (int j = 0; j < cnt; j++){
        size_t idx = (size_t)(base + j)*H + head;
        float p = __expf(ep[idx] - m);
        ep[idx] = p;
        dn += p;
    }
    den[t]   = dn;
    pSelf[t] = ps;
}

// ---------------- C: wave-per-node weighted gather-sum (no softmax in loop) ----------
template<int H, int CPL, int LAYER>
__global__ __launch_bounds__(256) void k_gat(const unsigned short* __restrict__ hlin,
        const float* __restrict__ ep, const float* __restrict__ den, const float* __restrict__ pSelf,
        const int* __restrict__ rowptr, const int* __restrict__ colx,
        const float* __restrict__ bias, const float* __restrict__ gate,
        unsigned short* __restrict__ out_bf, float* __restrict__ out_f, int N)
{
    constexpr int C = H*64;
    constexpr uint32 RB = C*2;               // bf16 row bytes
    int lane = threadIdx.x & 63, wid = threadIdx.x >> 6;
    int n = blockIdx.x*4 + wid;
    if (n >= N) return;
    const int c0 = lane*CPL;
    const int head = c0 >> 6;
    const int base = rowptr[n];
    const int cnt  = rowptr[n+1] - base;
    const char* hbase = (const char*)hlin + (uint32)c0*2;

    float acc[CPL];
    {
        float psf = pSelf[(uint32)n*H + head];
        if constexpr (CPL == 4){
            ushort4 v = *(const ushort4*)(hbase + (size_t)(uint32)n*RB);
            acc[0] = psf*bf2f(v.x); acc[1] = psf*bf2f(v.y);
            acc[2] = psf*bf2f(v.z); acc[3] = psf*bf2f(v.w);
        } else {
            uint32 v = *(const uint32*)(hbase + (size_t)(uint32)n*RB);
            acc[0] = psf*bf2f((unsigned short)(v & 0xffff));
            acc[1] = psf*bf2f((unsigned short)(v >> 16));
        }
    }
    for (int i = 0; i < cnt; i += 4){
        int idx[4], sk[4];
        #pragma unroll
        for (int k = 0; k < 4; k++){
            int ii = i + k; if (ii > cnt-1) ii = cnt-1;
            idx[k] = base + ii;
        }
        #pragma unroll
        for (int k = 0; k < 4; k++) sk[k] = colx[idx[k]];
        float pk[4];
        #pragma unroll
        for (int k = 0; k < 4; k++){
            float pv = ep[(size_t)(uint32)idx[k]*H + head];   // position-indexed: no colx dep
            pk[k] = (i + k < cnt) ? pv : 0.f;
        }
        if constexpr (CPL == 4){
            ushort4 h4[4];
            #pragma unroll
            for (int k = 0; k < 4; k++) h4[k] = *(const ushort4*)(hbase + (size_t)(uint32)sk[k]*RB);
            #pragma unroll
            for (int k = 0; k < 4; k++){
                acc[0] += pk[k]*bf2f(h4[k].x);
                acc[1] += pk[k]*bf2f(h4[k].y);
                acc[2] += pk[k]*bf2f(h4[k].z);
                acc[3] += pk[k]*bf2f(h4[k].w);
            }
        } else {
            uint32 h2v[4];
            #pragma unroll
            for (int k = 0; k < 4; k++) h2v[k] = *(const uint32*)(hbase + (size_t)(uint32)sk[k]*RB);
            #pragma unroll
            for (int k = 0; k < 4; k++){
                acc[0] += pk[k]*bf2f((unsigned short)(h2v[k] & 0xffff));
                acc[1] += pk[k]*bf2f((unsigned short)(h2v[k] >> 16));
            }
        }
    }

    float inv = 1.f/(den[(uint32)n*H + head] + 1e-16f);
    if constexpr (LAYER == 1){
        unsigned short o[CPL];
        #pragma unroll
        for (int j = 0; j < CPL; j++){
            float r = acc[j]*inv + bias[c0 + j];
            r = (r > 0.f) ? r : (__expf(r) - 1.f);   // elu
            o[j] = f2bf(r);
        }
        if constexpr (CPL == 4){
            ushort4 ov; ov.x = o[0]; ov.y = o[1]; ov.z = o[2]; ov.w = o[3];
            *(ushort4*)&out_bf[(size_t)n*C + c0] = ov;
        }
    } else {
        float o[CPL];
        #pragma unroll
        for (int j = 0; j < CPL; j++){
            float r = acc[j]*inv + bias[c0 + j];
            r = (r > 0.f) ? r : (__expf(r) - 1.f);   // elu
            o[j] = r*gate[(c0 + j) & 63];
        }
        if constexpr (CPL == 2){
            *(float2*)&out_f[(size_t)n*C + c0] = make_float2(o[0], o[1]);
        }
    }
}

// ---------------- attn MLP via MFMA: attn = sigmoid(relu(outh@aw1+ab1)@aw2+ab2) -------
__global__ __launch_bounds__(256) void k_attn_mfma(const float* __restrict__ outh,
        const unsigned short* __restrict__ Wfa, const float* __restrict__ ab1,
        const float* __restrict__ aw2, const float* __restrict__ ab2,
        float* __restrict__ attn, int N)
{
    __shared__ unsigned short Af[4*8*64*8];   // 32 KB: [kstep s][rowtile rt][lane][8]
    const int tid = threadIdx.x;
    const int l   = tid & 63;
    const int w   = tid >> 6;
    const int n0  = blockIdx.x * 128;

    const int r  = tid >> 1;
    const int kh = tid & 1;
    const int rt8 = r >> 4, rr = r & 15;
    int crow = n0 + r; if (crow > N-1) crow = N-1;
    const float* src = outh + (size_t)crow*C2 + kh*16;
    #pragma unroll
    for (int s = 0; s < 4; s++){
        float4 a = *(const float4*)(src + s*32 + 0);
        float4 b = *(const float4*)(src + s*32 + 4);
        float4 c = *(const float4*)(src + s*32 + 8);
        float4 d = *(const float4*)(src + s*32 + 12);
        uint4 u0, u1;
        u0.x = pack2(a.x, a.y); u0.y = pack2(a.z, a.w);
        u0.z = pack2(b.x, b.y); u0.w = pack2(b.z, b.w);
        u1.x = pack2(c.x, c.y); u1.y = pack2(c.z, c.w);
        u1.z = pack2(d.x, d.y); u1.w = pack2(d.z, d.w);
        int d0 = ((s*8 + rt8)*64 + (kh*2)*16 + rr)*8;
        *(uint4*)&Af[d0]       = u0;
        *(uint4*)&Af[d0 + 128] = u1;
    }
    __syncthreads();

    f32x4 acc[4][2];
    #pragma unroll
    for (int i = 0; i < 4; i++)
        #pragma unroll
        for (int rt = 0; rt < 2; rt++)
            acc[i][rt] = (f32x4){0.f, 0.f, 0.f, 0.f};

    #pragma unroll
    for (int s = 0; s < 4; s++){
        bf16x8 af[2];
        #pragma unroll
        for (int rt = 0; rt < 2; rt++)
            af[rt] = __builtin_bit_cast(bf16x8, *(const uint4*)&Af[((s*8 + w*2 + rt)*64 + l)*8]);
        #pragma unroll
        for (int i = 0; i < 4; i++){
            bf16x8 bw = __builtin_bit_cast(bf16x8, *(const uint4*)&Wfa[((size_t)(s*4 + i)*64 + l)*8]);
            #pragma unroll
            for (int rt = 0; rt < 2; rt++)
                acc[i][rt] = __builtin_amdgcn_mfma_f32_16x16x32_bf16(bw, af[rt], acc[i][rt], 0, 0, 0);
        }
    }

    const int g = l >> 4;
    float4 abv[4], awv[4];
    #pragma unroll
    for (int i = 0; i < 4; i++){
        abv[i] = *(const float4*)&ab1[i*16 + g*4];
        awv[i] = *(const float4*)&aw2[i*16 + g*4];
    }
    float b2v = ab2[0];
    #pragma unroll
    for (int rt = 0; rt < 2; rt++){
        int node = n0 + (w*2 + rt)*16 + (l & 15);
        float part = 0.f;
        #pragma unroll
        for (int i = 0; i < 4; i++){
            float v0 = fmaxf(acc[i][rt][0] + abv[i].x, 0.f);
            float v1 = fmaxf(acc[i][rt][1] + abv[i].y, 0.f);
            float v2 = fmaxf(acc[i][rt][2] + abv[i].z, 0.f);
            float v3 = fmaxf(acc[i][rt][3] + abv[i].w, 0.f);
            part += v0*awv[i].x + v1*awv[i].y + v2*awv[i].z + v3*awv[i].w;
        }
        part += __shfl_xor(part, 16, 64);
        part += __shfl_xor(part, 32, 64);
        if (g == 0 && node < N)
            attn[node] = 1.f/(1.f + __expf(-(part + b2v)));
    }
}

extern "C" void kernel_launch(void* const* d_in, const int* in_sizes, int n_in,
                              void* d_out, int out_size, void* d_ws, size_t ws_size,
                              hipStream_t stream)
{
    const float* x    = (const float*)d_in[0];
    const int*   ei   = (const int*)  d_in[1];
    const float* pad  = (const float*)d_in[2];
    const float* W1   = (const float*)d_in[3];
    const float* as1  = (const float*)d_in[4];
    const float* ad1  = (const float*)d_in[5];
    const float* b1   = (const float*)d_in[6];
    const float* W2   = (const float*)d_in[7];
    const float* as2  = (const float*)d_in[8];
    const float* ad2  = (const float*)d_in[9];
    const float* b2   = (const float*)d_in[10];
    const float* aw1  = (const float*)d_in[11];
    const float* ab1  = (const float*)d_in[12];
    const float* aw2  = (const float*)d_in[13];
    const float* ab2  = (const float*)d_in[14];
    const float* gw   = (const float*)d_in[15];
    const float* gb   = (const float*)d_in[16];

    const int N = in_sizes[0] / IN_DIM;
    const int E = in_sizes[1] / 2;

    float* outh    = (float*)d_out;
    float* outattn = outh + (size_t)N*C2;

    char* w = (char*)d_ws;
    auto alloc = [&](size_t bytes)->char*{
        char* p = w;
        w += (bytes + 255) & ~(size_t)255;
        return p;
    };
    unsigned short* h1  = (unsigned short*)alloc((size_t)N*C1*2);
    unsigned short* x2  = (unsigned short*)alloc((size_t)N*C1*2);
    unsigned short* h2  = (unsigned short*)alloc((size_t)N*C2*2);
    char*           xpad= alloc(65536);   // xs overrun guard (last 64-row block)
    float* als1 = (float*)alloc((size_t)N*4*4);
    float* ald1 = (float*)alloc((size_t)N*4*4);
    float* als2 = (float*)alloc((size_t)N*2*4);
    float* ald2 = (float*)alloc((size_t)N*2*4);
    int* deg    = (int*)alloc((size_t)N*4);
    int* cur    = (int*)alloc((size_t)N*4);
    int* rowptr = (int*)alloc((size_t)(N+1)*4);
    int* colx   = (int*)alloc((size_t)E*4);
    int* dstx   = (int*)alloc((size_t)E*4);
    int* part   = (int*)alloc(512*4);
    unsigned short* Wf1 = (unsigned short*)alloc((size_t)12*16*64*8*2);
    unsigned short* Wf2 = (unsigned short*)alloc((size_t)8*8*64*8*2);
    unsigned short* Wfa = (unsigned short*)alloc((size_t)4*4*64*8*2);
    float* c1v  = (float*)alloc(C1*4);
    float* gate = (float*)alloc(HID*4);
    (void)xpad;

    // Lifetime-based aliases (no new footprint):
    // xs (swizzled bf16 x, nbG*48KB) lives in x2+h2+xpad — dead before gat1 writes x2.
    unsigned short* xs = x2;
    float* ep1    = (float*)h2;                                   // E*4 floats (after gemm1)
    float* den1   = (float*)((char*)h2 + (size_t)E*16);           // N*4 floats
    float* pSelf1 = (float*)((char*)h2 + (size_t)E*16 + (size_t)N*16);
    float* ep2    = (float*)x2;                                   // E*2 floats
    float* den2   = (float*)((char*)x2 + (size_t)E*8);            // N*2 floats
    float* pSelf2 = (float*)((char*)x2 + (size_t)E*8 + (size_t)N*8);

    const int nbN = (N + 255)/256;
    const int nbE = (E + 255)/256;
    const int nbW = (N + 3)/4;        // wave-per-node kernels
    const int nbG = (N + 63)/64;      // gemm row blocks (64-row tiles)
    const int nbA = (N + 127)/128;    // attn-MLP row blocks

    // weight swizzles + constants (independent of CSR)
    k_cvtW <<<(192+3)/4, 256, 0, stream>>>(W1, Wf1, C1, 16, 192);
    k_cvtW <<<(64+3)/4,  256, 0, stream>>>(W2, Wf2, C2, 8, 64);
    k_cvtW <<<(16+3)/4,  256, 0, stream>>>(aw1, Wfa, HID, 4, 16);
    k_prep <<<1, 256, 0, stream>>>(W1, pad, gw, gb, c1v, gate);

    // x -> swizzled bf16 (sequential-read streaming)
    k_cvtX <<<nbG, 256, 0, stream>>>(x, xs, N);

    // CSR by destination
    k_zero   <<<nbN, 256, 0, stream>>>(deg, cur, N);
    k_hist   <<<nbE, 256, 0, stream>>>(ei, deg, E);
    k_scan1  <<<nbN, 256, 0, stream>>>(deg, rowptr, part, N);
    k_scan2  <<<1, 512, 0, stream>>>(part, nbN);
    k_scan3  <<<nbN, 256, 0, stream>>>(rowptr, part, N, E);
    k_scatter<<<nbE, 256, 0, stream>>>(ei, rowptr, cur, colx, dstx, E);

    // ---- layer 1 ----
    k_gemm1_mfma<<<nbG, 512, 0, stream>>>(xs, Wf1, c1v, as1, ad1, h1, als1, ald1, N);
    k_elogit<4><<<nbE, 256, 0, stream>>>(colx, dstx, als1, ald1, ep1, E);
    k_segsm<4> <<<(N*4 + 255)/256, 256, 0, stream>>>(rowptr, als1, ald1, ep1, den1, pSelf1, N*4);
    k_gat<4,4,1><<<nbW, 256, 0, stream>>>(h1, ep1, den1, pSelf1, rowptr, colx, b1,
                                          nullptr, x2, nullptr, N);

    // ---- layer 2 ----
    k_gemm2_mfma<<<nbG, 256, 0, stream>>>(x2, Wf2, as2, ad2, h2, als2, ald2, N);
    k_elogit<2><<<nbE, 256, 0, stream>>>(colx, dstx, als2, ald2, ep2, E);
    k_segsm<2> <<<(N*2 + 255)/256, 256, 0, stream>>>(rowptr, als2, ald2, ep2, den2, pSelf2, N*2);
    k_gat<2,2,2><<<nbW, 256, 0, stream>>>(h2, ep2, den2, pSelf2, rowptr, colx, b2,
                                          gate, nullptr, outh, N);

    // ---- attention-score MLP (MFMA) ----
    k_attn_mfma<<<nbA, 256, 0, stream>>>(outh, Wfa, ab1, aw2, ab2, outattn, N);
}

// Round 15
// 301.589 us; speedup vs baseline: 1.1567x; 1.1567x over previous
//
#include <hip/hip_runtime.h>
#include <hip/hip_bf16.h>
#include <stdint.h>

#define IN_DIM 384
#define HID 64
#define C1 256   // 4 heads * 64
#define C2 128   // 2 heads * 64

typedef unsigned int uint32;
typedef __bf16 bf16x8 __attribute__((ext_vector_type(8)));
typedef float f32x4 __attribute__((ext_vector_type(4)));

static __device__ __forceinline__ float bf2f(unsigned short u){
    return __uint_as_float(((uint32)u) << 16);
}
static __device__ __forceinline__ unsigned short f2bf(float x){
    uint32 u = __float_as_uint(x);
    return (unsigned short)((u + 0x7FFFu + ((u >> 16) & 1u)) >> 16);
}
static __device__ __forceinline__ uint32 pack2(float a, float b){
    return (uint32)f2bf(a) | ((uint32)f2bf(b) << 16);
}

// ---------------- CSR build ----------------
__global__ void k_zero(int* deg, int* cur, int N){
    int i = blockIdx.x*256 + threadIdx.x;
    if (i < N){ deg[i] = 0; cur[i] = 0; }
}
__global__ void k_hist(const int* __restrict__ ei, int* deg, int E){
    int i = blockIdx.x*256 + threadIdx.x;
    if (i < E) atomicAdd(&deg[ei[E + i]], 1);
}
__global__ void k_scan1(const int* __restrict__ deg, int* rowptr, int* part, int N){
    __shared__ int s[256];
    int tid = threadIdx.x;
    int i = blockIdx.x*256 + tid;
    int v = (i < N) ? deg[i] : 0;
    s[tid] = v; __syncthreads();
    for (int off = 1; off < 256; off <<= 1){
        int t = (tid >= off) ? s[tid - off] : 0;
        __syncthreads();
        s[tid] += t;
        __syncthreads();
    }
    if (i < N) rowptr[i] = s[tid] - v;
    if (tid == 255) part[blockIdx.x] = s[tid];
}
__global__ void k_scan2(int* part, int nb){
    __shared__ int s[512];
    int tid = threadIdx.x;
    int v = (tid < nb) ? part[tid] : 0;
    s[tid] = v; __syncthreads();
    for (int off = 1; off < 512; off <<= 1){
        int t = (tid >= off) ? s[tid - off] : 0;
        __syncthreads();
        s[tid] += t;
        __syncthreads();
    }
    if (tid < nb) part[tid] = s[tid] - v;
}
__global__ void k_scan3(int* rowptr, const int* __restrict__ part, int N, int E){
    int i = blockIdx.x*256 + threadIdx.x;
    if (i < N) rowptr[i] += part[blockIdx.x];
    if (i == 0) rowptr[N] = E;
}
__global__ void k_scatter(const int* __restrict__ ei, const int* __restrict__ rowptr,
                          int* cur, int* colx, int* dstx, int E){
    int i = blockIdx.x*256 + threadIdx.x;
    if (i < E){
        int d = ei[E + i];
        int pos = atomicAdd(&cur[d], 1);
        int p = rowptr[d] + pos;
        colx[p] = ei[i];
        dstx[p] = d;
    }
}

// ---------------- weight pre-swizzle: contiguous-k fragment order ----------------
// Wf[unit = ku*ntiles+ct][lane l][j] = W[k = ku*32 + 8*(l>>4) + j][ct*16 + (l&15)]
__global__ __launch_bounds__(256) void k_cvtW(const float* __restrict__ W,
        unsigned short* __restrict__ Wf, int ncol, int ntiles, int nunits){
    int unit = blockIdx.x*4 + (threadIdx.x >> 6);
    if (unit >= nunits) return;
    int l = threadIdx.x & 63;
    int s = unit / ntiles, ct = unit % ntiles;
    int col = ct*16 + (l & 15);
    int g = l >> 4;
    unsigned short o[8];
    #pragma unroll
    for (int j = 0; j < 8; j++){
        int k = s*32 + g*8 + j;
        o[j] = f2bf(W[(size_t)k*ncol + col]);
    }
    ushort4* dst = (ushort4*)&Wf[((size_t)unit*64 + l)*8];
    dst[0] = make_ushort4(o[0], o[1], o[2], o[3]);
    dst[1] = make_ushort4(o[4], o[5], o[6], o[7]);
}

// ---------------- constant precompute: pad bias, emotion gate ----------
__global__ __launch_bounds__(256) void k_prep(const float* __restrict__ W1,
        const float* __restrict__ pad, const float* __restrict__ gw, const float* __restrict__ gb,
        float* __restrict__ c1v, float* __restrict__ gate){
    int tid = threadIdx.x;
    c1v[tid] = pad[0]*W1[(size_t)(IN_DIM+0)*C1 + tid]
             + pad[1]*W1[(size_t)(IN_DIM+1)*C1 + tid]
             + pad[2]*W1[(size_t)(IN_DIM+2)*C1 + tid];
    if (tid < HID){
        float g = pad[0]*gw[0*HID + tid] + pad[1]*gw[1*HID + tid] + pad[2]*gw[2*HID + tid] + gb[tid];
        gate[tid] = 1.f/(1.f + __expf(-g));
    }
}

// ---------------- GEMM1 (MFMA): h1 = [x|pad]@W1 + fused al1 epilogue ----------------
// 512 thr, 64 rows/block. Staging: 12 NAMED float4 loads/thread covering the block's
// 96KB x-range SEQUENTIALLY (lane i reads base+16i), pack to bf16, scatter only into
// LDS (row-major [64][384] bf16, XOR-swizzled byte ^ ((row&7)<<4)). ONE barrier,
// then 12 k-units of MFMA with swizzled ds_read_b128 fragment reads + W reg-prefetch.
// Wave w: wr = w>>2 (32-row half), wc = w&3 (head). acc[4][2] = 32 AGPR.
__global__ __launch_bounds__(512) void k_gemm1_mfma(const float* __restrict__ x,
        const unsigned short* __restrict__ Wf, const float* __restrict__ c1v,
        const float* __restrict__ as1, const float* __restrict__ ad1,
        unsigned short* __restrict__ h1, float* __restrict__ als, float* __restrict__ ald, int N)
{
    __shared__ unsigned short Af[24576];    // 48 KB: bf16 [64][384] + XOR swizzle
    const int tid = threadIdx.x;
    const int l   = tid & 63;
    const int w   = tid >> 6;       // 0..7
    const int wr  = w >> 2;         // row half
    const int wc  = w & 3;          // head
    const int n0  = blockIdx.x * 64;
    const bool full = (n0 + 64 <= N);

    // ---- sequential load phase (12 independent named loads) ----
    float4 rx[12];
    if (full){
        const float* bp = x + (size_t)n0*IN_DIM;
        #pragma unroll
        for (int it = 0; it < 12; ++it)
            rx[it] = *(const float4*)(bp + (size_t)(it*512 + tid)*4);
    } else {
        #pragma unroll
        for (int it = 0; it < 12; ++it){
            int f = it*512 + tid;
            int row = f/96, k4 = f - row*96;
            int n = n0 + row; if (n > N-1) n = N-1;
            rx[it] = *(const float4*)(x + (size_t)n*IN_DIM + k4*4);
        }
    }
    // ---- pack + swizzled LDS store ----
    #pragma unroll
    for (int it = 0; it < 12; ++it){
        uint32 f = (uint32)(it*512 + tid);
        uint32 row = f/96;
        uint32 byte = f*8;                        // linear row-major bf16 offset
        uint32 swz = byte ^ ((row & 7) << 4);
        uint2 v = make_uint2(pack2(rx[it].x, rx[it].y), pack2(rx[it].z, rx[it].w));
        *(uint2*)((char*)Af + swz) = v;
    }

    f32x4 acc[4][2];
    #pragma unroll
    for (int i = 0; i < 4; i++)
        #pragma unroll
        for (int rt = 0; rt < 2; rt++)
            acc[i][rt] = (f32x4){0.f, 0.f, 0.f, 0.f};

    uint4 wcur[4], wnxt[4];
    {
        const unsigned short* p = Wf + ((size_t)(wc*4)*64 + l)*8;
        #pragma unroll
        for (int i = 0; i < 4; i++) wcur[i] = *(const uint4*)(p + (size_t)i*512);
    }
    __syncthreads();

    // fragment addresses: row = (wr*2+rt)*16 + (l&15), k-off = ku*64 + (l>>4)*16 bytes
    const uint32 frow0 = (uint32)((wr*2 + 0)*16 + (l & 15));
    const uint32 frow1 = (uint32)((wr*2 + 1)*16 + (l & 15));
    const uint32 fb0 = frow0*768 + ((uint32)(l >> 4) << 4);
    const uint32 fb1 = frow1*768 + ((uint32)(l >> 4) << 4);
    const uint32 fx0 = (frow0 & 7) << 4;
    const uint32 fx1 = (frow1 & 7) << 4;

    for (int ku = 0; ku < 12; ++ku){
        if (ku < 11){
            const unsigned short* p = Wf + ((size_t)((ku+1)*16 + wc*4)*64 + l)*8;
            #pragma unroll
            for (int i = 0; i < 4; i++) wnxt[i] = *(const uint4*)(p + (size_t)i*512);
        }
        bf16x8 af[2];
        af[0] = __builtin_bit_cast(bf16x8, *(const uint4*)((char*)Af + ((fb0 + ku*64) ^ fx0)));
        af[1] = __builtin_bit_cast(bf16x8, *(const uint4*)((char*)Af + ((fb1 + ku*64) ^ fx1)));
        #pragma unroll
        for (int i = 0; i < 4; i++){
            bf16x8 bw = __builtin_bit_cast(bf16x8, wcur[i]);
            #pragma unroll
            for (int rt = 0; rt < 2; rt++)
                acc[i][rt] = __builtin_amdgcn_mfma_f32_16x16x32_bf16(bw, af[rt], acc[i][rt], 0, 0, 0);
        }
        if (ku < 11){
            #pragma unroll
            for (int i = 0; i < 4; i++) wcur[i] = wnxt[i];
        }
    }

    const int g = l >> 4;
    float4 cvv[4], av[4], dv[4];
    #pragma unroll
    for (int i = 0; i < 4; i++){
        int cl = i*16 + g*4;
        cvv[i] = *(const float4*)&c1v[wc*64 + cl];
        av[i]  = *(const float4*)&as1[wc*64 + cl];
        dv[i]  = *(const float4*)&ad1[wc*64 + cl];
    }
    #pragma unroll
    for (int rt = 0; rt < 2; rt++){
        int node = n0 + (wr*2 + rt)*16 + (l & 15);
        bool ok = node < N;
        float ps = 0.f, pd = 0.f;
        #pragma unroll
        for (int i = 0; i < 4; i++){
            float h0 = acc[i][rt][0] + cvv[i].x;
            float h1v = acc[i][rt][1] + cvv[i].y;
            float h2v = acc[i][rt][2] + cvv[i].z;
            float h3v = acc[i][rt][3] + cvv[i].w;
            ps += h0*av[i].x + h1v*av[i].y + h2v*av[i].z + h3v*av[i].w;
            pd += h0*dv[i].x + h1v*dv[i].y + h2v*dv[i].z + h3v*dv[i].w;
            if (ok){
                ushort4 o = make_ushort4(f2bf(h0), f2bf(h1v), f2bf(h2v), f2bf(h3v));
                *(ushort4*)&h1[(size_t)node*C1 + wc*64 + i*16 + g*4] = o;
            }
        }
        ps += __shfl_xor(ps, 16, 64); ps += __shfl_xor(ps, 32, 64);
        pd += __shfl_xor(pd, 16, 64); pd += __shfl_xor(pd, 32, 64);
        if (ok && g == 0){
            als[(size_t)node*4 + wc] = ps;
            ald[(size_t)node*4 + wc] = pd;
        }
    }
}

// ---------------- GEMM2 (MFMA): h2 = x2 @ W2 + fused al2 epilogue ----------------
__global__ __launch_bounds__(256) void k_gemm2_mfma(const unsigned short* __restrict__ x2,
        const unsigned short* __restrict__ Wf,
        const float* __restrict__ as2, const float* __restrict__ ad2,
        unsigned short* __restrict__ h2, float* __restrict__ als, float* __restrict__ ald, int N)
{
    __shared__ unsigned short Af[2][4*64*8];   // 2 x 4KB
    const int tid = threadIdx.x;
    const int l   = tid & 63;
    const int w   = tid >> 6;
    const int wr  = w >> 1, wc = w & 1;
    const int n0  = blockIdx.x * 64;

    const int sr  = tid >> 2;
    const int kc  = tid & 3;
    const int d0  = ((sr >> 4)*64 + kc*16 + (sr & 15))*8;
    int crow = n0 + sr; if (crow > N-1) crow = N-1;
    const unsigned short* xrow = x2 + (size_t)crow*C1 + kc*8;

    f32x4 acc[4][2];
    #pragma unroll
    for (int i = 0; i < 4; i++)
        #pragma unroll
        for (int rt = 0; rt < 2; rt++)
            acc[i][rt] = (f32x4){0.f, 0.f, 0.f, 0.f};

    uint4 p0, wcur[4], wnxt[4];
    p0 = *(const uint4*)(xrow);
    *(uint4*)&Af[0][d0] = p0;
    {
        const unsigned short* p = Wf + ((size_t)(wc*4)*64 + l)*8;
        #pragma unroll
        for (int i = 0; i < 4; i++) wcur[i] = *(const uint4*)(p + (size_t)i*512);
    }
    __syncthreads();

    for (int s = 0; s < 8; ++s){
        if (s < 7){
            p0 = *(const uint4*)(xrow + (s+1)*32);
            const unsigned short* p = Wf + ((size_t)((s+1)*8 + wc*4)*64 + l)*8;
            #pragma unroll
            for (int i = 0; i < 4; i++) wnxt[i] = *(const uint4*)(p + (size_t)i*512);
        }
        bf16x8 af[2];
        #pragma unroll
        for (int rt = 0; rt < 2; rt++)
            af[rt] = __builtin_bit_cast(bf16x8, *(const uint4*)&Af[s&1][((wr*2 + rt)*64 + l)*8]);
        #pragma unroll
        for (int i = 0; i < 4; i++){
            bf16x8 bw = __builtin_bit_cast(bf16x8, wcur[i]);
            #pragma unroll
            for (int rt = 0; rt < 2; rt++)
                acc[i][rt] = __builtin_amdgcn_mfma_f32_16x16x32_bf16(bw, af[rt], acc[i][rt], 0, 0, 0);
        }
        if (s < 7){
            *(uint4*)&Af[(s+1)&1][d0] = p0;
            __syncthreads();
            #pragma unroll
            for (int i = 0; i < 4; i++) wcur[i] = wnxt[i];
        }
    }

    const int g = l >> 4;
    float4 av[4], dv[4];
    #pragma unroll
    for (int i = 0; i < 4; i++){
        int cl = i*16 + g*4;
        av[i] = *(const float4*)&as2[wc*64 + cl];
        dv[i] = *(const float4*)&ad2[wc*64 + cl];
    }
    #pragma unroll
    for (int rt = 0; rt < 2; rt++){
        int node = n0 + wr*32 + rt*16 + (l & 15);
        bool ok = node < N;
        float ps = 0.f, pd = 0.f;
        #pragma unroll
        for (int i = 0; i < 4; i++){
            float h0 = acc[i][rt][0], h1v = acc[i][rt][1];
            float h2v = acc[i][rt][2], h3v = acc[i][rt][3];
            ps += h0*av[i].x + h1v*av[i].y + h2v*av[i].z + h3v*av[i].w;
            pd += h0*dv[i].x + h1v*dv[i].y + h2v*dv[i].z + h3v*dv[i].w;
            if (ok){
                ushort4 o = make_ushort4(f2bf(h0), f2bf(h1v), f2bf(h2v), f2bf(h3v));
                *(ushort4*)&h2[(size_t)node*C2 + wc*64 + i*16 + g*4] = o;
            }
        }
        ps += __shfl_xor(ps, 16, 64); ps += __shfl_xor(ps, 32, 64);
        pd += __shfl_xor(pd, 16, 64); pd += __shfl_xor(pd, 32, 64);
        if (ok && g == 0){
            als[(size_t)node*2 + wc] = ps;
            ald[(size_t)node*2 + wc] = pd;
        }
    }
}

// ---------------- A: edge-parallel logits e = leaky(als[src]+ald[dst]) ----------------
template<int H>
__global__ __launch_bounds__(256) void k_elogit(const int* __restrict__ colx,
        const int* __restrict__ dstx, const float* __restrict__ als,
        const float* __restrict__ ald, float* __restrict__ ep, int E)
{
    int i = blockIdx.x*256 + threadIdx.x;
    if (i >= E) return;
    int s = colx[i], d = dstx[i];
    if constexpr (H == 4){
        float4 a = *(const float4*)&als[(size_t)s*4];
        float4 b = *(const float4*)&ald[(size_t)d*4];
        float4 e;
        e.x = a.x + b.x; e.x = fmaxf(e.x, 0.2f*e.x);
        e.y = a.y + b.y; e.y = fmaxf(e.y, 0.2f*e.y);
        e.z = a.z + b.z; e.z = fmaxf(e.z, 0.2f*e.z);
        e.w = a.w + b.w; e.w = fmaxf(e.w, 0.2f*e.w);
        *(float4*)&ep[(size_t)i*4] = e;
    } else {
        float2 a = *(const float2*)&als[(size_t)s*2];
        float2 b = *(const float2*)&ald[(size_t)d*2];
        float2 e;
        e.x = a.x + b.x; e.x = fmaxf(e.x, 0.2f*e.x);
        e.y = a.y + b.y; e.y = fmaxf(e.y, 0.2f*e.y);
        *(float2*)&ep[(size_t)i*2] = e;
    }
}

// ---------------- B: thread per (node,head) segment softmax; ep <- p (in place) -------
template<int H>
__global__ __launch_bounds__(256) void k_segsm(const int* __restrict__ rowptr,
        const float* __restrict__ als, const float* __restrict__ ald,
        float* __restrict__ ep, float* __restrict__ den, float* __restrict__ pSelf, int NH)
{
    int t = blockIdx.x*256 + threadIdx.x;
    if (t >= NH) return;
    int node = t / H;
    int head = t - node*H;
    int base = rowptr[node];
    int cnt  = rowptr[node+1] - base;
    float es = als[t] + ald[t];
    es = fmaxf(es, 0.2f*es);
    float m = es;
    for (int j = 0; j < cnt; j++)
        m = fmaxf(m, ep[(size_t)(base + j)*H + head]);
    float ps = __expf(es - m);
    float dn = ps;
    for (int j = 0; j < cnt; j++){
        size_t idx = (size_t)(base + j)*H + head;
        float p = __expf(ep[idx] - m);
        ep[idx] = p;
        dn += p;
    }
    den[t]   = dn;
    pSelf[t] = ps;
}

// ---------------- C: wave-per-node weighted gather-sum (no softmax in loop) ----------
template<int H, int CPL, int LAYER>
__global__ __launch_bounds__(256) void k_gat(const unsigned short* __restrict__ hlin,
        const float* __restrict__ ep, const float* __restrict__ den, const float* __restrict__ pSelf,
        const int* __restrict__ rowptr, const int* __restrict__ colx,
        const float* __restrict__ bias, const float* __restrict__ gate,
        unsigned short* __restrict__ out_bf, float* __restrict__ out_f, int N)
{
    constexpr int C = H*64;
    constexpr uint32 RB = C*2;               // bf16 row bytes
    int lane = threadIdx.x & 63, wid = threadIdx.x >> 6;
    int n = blockIdx.x*4 + wid;
    if (n >= N) return;
    const int c0 = lane*CPL;
    const int head = c0 >> 6;
    const int base = rowptr[n];
    const int cnt  = rowptr[n+1] - base;
    const char* hbase = (const char*)hlin + (uint32)c0*2;

    float acc[CPL];
    {
        float psf = pSelf[(uint32)n*H + head];
        if constexpr (CPL == 4){
            ushort4 v = *(const ushort4*)(hbase + (size_t)(uint32)n*RB);
            acc[0] = psf*bf2f(v.x); acc[1] = psf*bf2f(v.y);
            acc[2] = psf*bf2f(v.z); acc[3] = psf*bf2f(v.w);
        } else {
            uint32 v = *(const uint32*)(hbase + (size_t)(uint32)n*RB);
            acc[0] = psf*bf2f((unsigned short)(v & 0xffff));
            acc[1] = psf*bf2f((unsigned short)(v >> 16));
        }
    }
    for (int i = 0; i < cnt; i += 4){
        int idx[4], sk[4];
        #pragma unroll
        for (int k = 0; k < 4; k++){
            int ii = i + k; if (ii > cnt-1) ii = cnt-1;
            idx[k] = base + ii;
        }
        #pragma unroll
        for (int k = 0; k < 4; k++) sk[k] = colx[idx[k]];
        float pk[4];
        #pragma unroll
        for (int k = 0; k < 4; k++){
            float pv = ep[(size_t)(uint32)idx[k]*H + head];   // position-indexed: no colx dep
            pk[k] = (i + k < cnt) ? pv : 0.f;
        }
        if constexpr (CPL == 4){
            ushort4 h4[4];
            #pragma unroll
            for (int k = 0; k < 4; k++) h4[k] = *(const ushort4*)(hbase + (size_t)(uint32)sk[k]*RB);
            #pragma unroll
            for (int k = 0; k < 4; k++){
                acc[0] += pk[k]*bf2f(h4[k].x);
                acc[1] += pk[k]*bf2f(h4[k].y);
                acc[2] += pk[k]*bf2f(h4[k].z);
                acc[3] += pk[k]*bf2f(h4[k].w);
            }
        } else {
            uint32 h2v[4];
            #pragma unroll
            for (int k = 0; k < 4; k++) h2v[k] = *(const uint32*)(hbase + (size_t)(uint32)sk[k]*RB);
            #pragma unroll
            for (int k = 0; k < 4; k++){
                acc[0] += pk[k]*bf2f((unsigned short)(h2v[k] & 0xffff));
                acc[1] += pk[k]*bf2f((unsigned short)(h2v[k] >> 16));
            }
        }
    }

    float inv = 1.f/(den[(uint32)n*H + head] + 1e-16f);
    if constexpr (LAYER == 1){
        unsigned short o[CPL];
        #pragma unroll
        for (int j = 0; j < CPL; j++){
            float r = acc[j]*inv + bias[c0 + j];
            r = (r > 0.f) ? r : (__expf(r) - 1.f);   // elu
            o[j] = f2bf(r);
        }
        if constexpr (CPL == 4){
            ushort4 ov; ov.x = o[0]; ov.y = o[1]; ov.z = o[2]; ov.w = o[3];
            *(ushort4*)&out_bf[(size_t)n*C + c0] = ov;
        }
    } else {
        float o[CPL];
        #pragma unroll
        for (int j = 0; j < CPL; j++){
            float r = acc[j]*inv + bias[c0 + j];
            r = (r > 0.f) ? r : (__expf(r) - 1.f);   // elu
            o[j] = r*gate[(c0 + j) & 63];
        }
        if constexpr (CPL == 2){
            *(float2*)&out_f[(size_t)n*C + c0] = make_float2(o[0], o[1]);
        }
    }
}

// ---------------- attn MLP via MFMA: attn = sigmoid(relu(outh@aw1+ab1)@aw2+ab2) -------
__global__ __launch_bounds__(256) void k_attn_mfma(const float* __restrict__ outh,
        const unsigned short* __restrict__ Wfa, const float* __restrict__ ab1,
        const float* __restrict__ aw2, const float* __restrict__ ab2,
        float* __restrict__ attn, int N)
{
    __shared__ unsigned short Af[4*8*64*8];   // 32 KB: [kstep s][rowtile rt][lane][8]
    const int tid = threadIdx.x;
    const int l   = tid & 63;
    const int w   = tid >> 6;
    const int n0  = blockIdx.x * 128;

    const int r  = tid >> 1;
    const int kh = tid & 1;
    const int rt8 = r >> 4, rr = r & 15;
    int crow = n0 + r; if (crow > N-1) crow = N-1;
    const float* src = outh + (size_t)crow*C2 + kh*16;
    #pragma unroll
    for (int s = 0; s < 4; s++){
        float4 a = *(const float4*)(src + s*32 + 0);
        float4 b = *(const float4*)(src + s*32 + 4);
        float4 c = *(const float4*)(src + s*32 + 8);
        float4 d = *(const float4*)(src + s*32 + 12);
        uint4 u0, u1;
        u0.x = pack2(a.x, a.y); u0.y = pack2(a.z, a.w);
        u0.z = pack2(b.x, b.y); u0.w = pack2(b.z, b.w);
        u1.x = pack2(c.x, c.y); u1.y = pack2(c.z, c.w);
        u1.z = pack2(d.x, d.y); u1.w = pack2(d.z, d.w);
        int d0 = ((s*8 + rt8)*64 + (kh*2)*16 + rr)*8;
        *(uint4*)&Af[d0]       = u0;
        *(uint4*)&Af[d0 + 128] = u1;
    }
    __syncthreads();

    f32x4 acc[4][2];
    #pragma unroll
    for (int i = 0; i < 4; i++)
        #pragma unroll
        for (int rt = 0; rt < 2; rt++)
            acc[i][rt] = (f32x4){0.f, 0.f, 0.f, 0.f};

    #pragma unroll
    for (int s = 0; s < 4; s++){
        bf16x8 af[2];
        #pragma unroll
        for (int rt = 0; rt < 2; rt++)
            af[rt] = __builtin_bit_cast(bf16x8, *(const uint4*)&Af[((s*8 + w*2 + rt)*64 + l)*8]);
        #pragma unroll
        for (int i = 0; i < 4; i++){
            bf16x8 bw = __builtin_bit_cast(bf16x8, *(const uint4*)&Wfa[((size_t)(s*4 + i)*64 + l)*8]);
            #pragma unroll
            for (int rt = 0; rt < 2; rt++)
                acc[i][rt] = __builtin_amdgcn_mfma_f32_16x16x32_bf16(bw, af[rt], acc[i][rt], 0, 0, 0);
        }
    }

    const int g = l >> 4;
    float4 abv[4], awv[4];
    #pragma unroll
    for (int i = 0; i < 4; i++){
        abv[i] = *(const float4*)&ab1[i*16 + g*4];
        awv[i] = *(const float4*)&aw2[i*16 + g*4];
    }
    float b2v = ab2[0];
    #pragma unroll
    for (int rt = 0; rt < 2; rt++){
        int node = n0 + (w*2 + rt)*16 + (l & 15);
        float part = 0.f;
        #pragma unroll
        for (int i = 0; i < 4; i++){
            float v0 = fmaxf(acc[i][rt][0] + abv[i].x, 0.f);
            float v1 = fmaxf(acc[i][rt][1] + abv[i].y, 0.f);
            float v2 = fmaxf(acc[i][rt][2] + abv[i].z, 0.f);
            float v3 = fmaxf(acc[i][rt][3] + abv[i].w, 0.f);
            part += v0*awv[i].x + v1*awv[i].y + v2*awv[i].z + v3*awv[i].w;
        }
        part += __shfl_xor(part, 16, 64);
        part += __shfl_xor(part, 32, 64);
        if (g == 0 && node < N)
            attn[node] = 1.f/(1.f + __expf(-(part + b2v)));
    }
}

extern "C" void kernel_launch(void* const* d_in, const int* in_sizes, int n_in,
                              void* d_out, int out_size, void* d_ws, size_t ws_size,
                              hipStream_t stream)
{
    const float* x    = (const float*)d_in[0];
    const int*   ei   = (const int*)  d_in[1];
    const float* pad  = (const float*)d_in[2];
    const float* W1   = (const float*)d_in[3];
    const float* as1  = (const float*)d_in[4];
    const float* ad1  = (const float*)d_in[5];
    const float* b1   = (const float*)d_in[6];
    const float* W2   = (const float*)d_in[7];
    const float* as2  = (const float*)d_in[8];
    const float* ad2  = (const float*)d_in[9];
    const float* b2   = (const float*)d_in[10];
    const float* aw1  = (const float*)d_in[11];
    const float* ab1  = (const float*)d_in[12];
    const float* aw2  = (const float*)d_in[13];
    const float* ab2  = (const float*)d_in[14];
    const float* gw   = (const float*)d_in[15];
    const float* gb   = (const float*)d_in[16];

    const int N = in_sizes[0] / IN_DIM;
    const int E = in_sizes[1] / 2;

    float* outh    = (float*)d_out;
    float* outattn = outh + (size_t)N*C2;

    char* w = (char*)d_ws;
    auto alloc = [&](size_t bytes)->char*{
        char* p = w;
        w += (bytes + 255) & ~(size_t)255;
        return p;
    };
    unsigned short* h1  = (unsigned short*)alloc((size_t)N*C1*2);
    unsigned short* x2  = (unsigned short*)alloc((size_t)N*C1*2);
    unsigned short* h2  = (unsigned short*)alloc((size_t)N*C2*2);
    float* als1 = (float*)alloc((size_t)N*4*4);
    float* ald1 = (float*)alloc((size_t)N*4*4);
    float* als2 = (float*)alloc((size_t)N*2*4);
    float* ald2 = (float*)alloc((size_t)N*2*4);
    int* deg    = (int*)alloc((size_t)N*4);
    int* cur    = (int*)alloc((size_t)N*4);
    int* rowptr = (int*)alloc((size_t)(N+1)*4);
    int* colx   = (int*)alloc((size_t)E*4);
    int* dstx   = (int*)alloc((size_t)E*4);
    int* part   = (int*)alloc(512*4);
    unsigned short* Wf1 = (unsigned short*)alloc((size_t)12*16*64*8*2);
    unsigned short* Wf2 = (unsigned short*)alloc((size_t)8*8*64*8*2);
    unsigned short* Wfa = (unsigned short*)alloc((size_t)4*4*64*8*2);
    float* c1v  = (float*)alloc(C1*4);
    float* gate = (float*)alloc(HID*4);

    // Lifetime-based aliases (no new footprint):
    float* ep1    = (float*)h2;                                   // E*4 floats
    float* den1   = (float*)((char*)h2 + (size_t)E*16);           // N*4 floats
    float* pSelf1 = (float*)((char*)h2 + (size_t)E*16 + (size_t)N*16);
    float* ep2    = (float*)x2;                                   // E*2 floats
    float* den2   = (float*)((char*)x2 + (size_t)E*8);            // N*2 floats
    float* pSelf2 = (float*)((char*)x2 + (size_t)E*8 + (size_t)N*8);

    const int nbN = (N + 255)/256;
    const int nbE = (E + 255)/256;
    const int nbW = (N + 3)/4;        // wave-per-node kernels
    const int nbG = (N + 63)/64;      // gemm row blocks (64-row tiles)
    const int nbA = (N + 127)/128;    // attn-MLP row blocks

    // weight swizzles + constants (independent of CSR)
    k_cvtW <<<(192+3)/4, 256, 0, stream>>>(W1, Wf1, C1, 16, 192);
    k_cvtW <<<(64+3)/4,  256, 0, stream>>>(W2, Wf2, C2, 8, 64);
    k_cvtW <<<(16+3)/4,  256, 0, stream>>>(aw1, Wfa, HID, 4, 16);
    k_prep <<<1, 256, 0, stream>>>(W1, pad, gw, gb, c1v, gate);

    // CSR by destination
    k_zero   <<<nbN, 256, 0, stream>>>(deg, cur, N);
    k_hist   <<<nbE, 256, 0, stream>>>(ei, deg, E);
    k_scan1  <<<nbN, 256, 0, stream>>>(deg, rowptr, part, N);
    k_scan2  <<<1, 512, 0, stream>>>(part, nbN);
    k_scan3  <<<nbN, 256, 0, stream>>>(rowptr, part, N, E);
    k_scatter<<<nbE, 256, 0, stream>>>(ei, rowptr, cur, colx, dstx, E);

    // ---- layer 1 ----
    k_gemm1_mfma<<<nbG, 512, 0, stream>>>(x, Wf1, c1v, as1, ad1, h1, als1, ald1, N);
    k_elogit<4><<<nbE, 256, 0, stream>>>(colx, dstx, als1, ald1, ep1, E);
    k_segsm<4> <<<(N*4 + 255)/256, 256, 0, stream>>>(rowptr, als1, ald1, ep1, den1, pSelf1, N*4);
    k_gat<4,4,1><<<nbW, 256, 0, stream>>>(h1, ep1, den1, pSelf1, rowptr, colx, b1,
                                          nullptr, x2, nullptr, N);

    // ---- layer 2 ----
    k_gemm2_mfma<<<nbG, 256, 0, stream>>>(x2, Wf2, as2, ad2, h2, als2, ald2, N);
    k_elogit<2><<<nbE, 256, 0, stream>>>(colx, dstx, als2, ald2, ep2, E);
    k_segsm<2> <<<(N*2 + 255)/256, 256, 0, stream>>>(rowptr, als2, ald2, ep2, den2, pSelf2, N*2);
    k_gat<2,2,2><<<nbW, 256, 0, stream>>>(h2, ep2, den2, pSelf2, rowptr, colx, b2,
                                          gate, nullptr, outh, N);

    // ---- attention-score MLP (MFMA) ----
    k_attn_mfma<<<nbA, 256, 0, stream>>>(outh, Wfa, ab1, aw2, ab2, outattn, N);
}

// Round 16
// 300.735 us; speedup vs baseline: 1.1600x; 1.0028x over previous
//
#include <hip/hip_runtime.h>
#include <hip/hip_bf16.h>
#include <stdint.h>

#define IN_DIM 384
#define HID 64
#define C1 256   // 4 heads * 64
#define C2 128   // 2 heads * 64

typedef unsigned int uint32;
typedef __bf16 bf16x8 __attribute__((ext_vector_type(8)));
typedef float f32x4 __attribute__((ext_vector_type(4)));

static __device__ __forceinline__ float bf2f(unsigned short u){
    return __uint_as_float(((uint32)u) << 16);
}
static __device__ __forceinline__ unsigned short f2bf(float x){
    uint32 u = __float_as_uint(x);
    return (unsigned short)((u + 0x7FFFu + ((u >> 16) & 1u)) >> 16);
}
static __device__ __forceinline__ uint32 pack2(float a, float b){
    return (uint32)f2bf(a) | ((uint32)f2bf(b) << 16);
}

// ---------------- CSR build (atomic-range variant: no prefix scan) ----------------
__global__ void k_zero(int* deg, int* cur, int* total, int N){
    int i = blockIdx.x*256 + threadIdx.x;
    if (i < N){ deg[i] = 0; cur[i] = 0; }
    if (i == 0) total[0] = 0;
}
__global__ void k_hist(const int* __restrict__ ei, int* deg, int E){
    int i = blockIdx.x*256 + threadIdx.x;
    if (i < E) atomicAdd(&deg[ei[E + i]], 1);
}
// each node grabs a contiguous range [rowptr[i], rowptr[i]+deg[i]) in arbitrary order
__global__ void k_range(const int* __restrict__ deg, int* rowptr, int* total, int N){
    int i = blockIdx.x*256 + threadIdx.x;
    if (i < N) rowptr[i] = atomicAdd(total, deg[i]);
}
__global__ void k_scatter(const int* __restrict__ ei, const int* __restrict__ rowptr,
                          int* cur, int* colx, int E){
    int i = blockIdx.x*256 + threadIdx.x;
    if (i < E){
        int d = ei[E + i];
        int pos = atomicAdd(&cur[d], 1);
        colx[rowptr[d] + pos] = ei[i];
    }
}

// ---------------- weight pre-swizzle: contiguous-k fragment order ----------------
// Wf[unit = ku*ntiles+ct][lane l][j] = W[k = ku*32 + 8*(l>>4) + j][ct*16 + (l&15)]
__global__ __launch_bounds__(256) void k_cvtW(const float* __restrict__ W,
        unsigned short* __restrict__ Wf, int ncol, int ntiles, int nunits){
    int unit = blockIdx.x*4 + (threadIdx.x >> 6);
    if (unit >= nunits) return;
    int l = threadIdx.x & 63;
    int s = unit / ntiles, ct = unit % ntiles;
    int col = ct*16 + (l & 15);
    int g = l >> 4;
    unsigned short o[8];
    #pragma unroll
    for (int j = 0; j < 8; j++){
        int k = s*32 + g*8 + j;
        o[j] = f2bf(W[(size_t)k*ncol + col]);
    }
    ushort4* dst = (ushort4*)&Wf[((size_t)unit*64 + l)*8];
    dst[0] = make_ushort4(o[0], o[1], o[2], o[3]);
    dst[1] = make_ushort4(o[4], o[5], o[6], o[7]);
}

// ---------------- constant precompute: pad bias, emotion gate ----------
__global__ __launch_bounds__(256) void k_prep(const float* __restrict__ W1,
        const float* __restrict__ pad, const float* __restrict__ gw, const float* __restrict__ gb,
        float* __restrict__ c1v, float* __restrict__ gate){
    int tid = threadIdx.x;
    c1v[tid] = pad[0]*W1[(size_t)(IN_DIM+0)*C1 + tid]
             + pad[1]*W1[(size_t)(IN_DIM+1)*C1 + tid]
             + pad[2]*W1[(size_t)(IN_DIM+2)*C1 + tid];
    if (tid < HID){
        float g = pad[0]*gw[0*HID + tid] + pad[1]*gw[1*HID + tid] + pad[2]*gw[2*HID + tid] + gb[tid];
        gate[tid] = 1.f/(1.f + __expf(-g));
    }
}

// ---------------- GEMM1 (MFMA): h1 = [x|pad]@W1 + fused al1 epilogue ----------------
// (round-9 structure: 64 rows x 256 cols, 4 waves, 96-float K staging, dbuf LDS)
__global__ __launch_bounds__(256) void k_gemm1_mfma(const float* __restrict__ x,
        const unsigned short* __restrict__ Wf, const float* __restrict__ c1v,
        const float* __restrict__ as1, const float* __restrict__ ad1,
        unsigned short* __restrict__ h1, float* __restrict__ als, float* __restrict__ ald, int N)
{
    __shared__ unsigned short Af[2][12*64*8];   // 2 x 12 KB
    const int tid = threadIdx.x;
    const int l   = tid & 63;
    const int w   = tid >> 6;
    const int n0  = blockIdx.x * 64;

    const int sr  = tid >> 2;
    const int kc  = tid & 3;
    const int rts = sr >> 4, srr = sr & 15;
    int dls[3];
    #pragma unroll
    for (int u = 0; u < 3; u++)
        dls[u] = ((u*4 + rts)*64 + kc*16 + srr)*8;
    int crow = n0 + sr; if (crow > N-1) crow = N-1;
    const float* xrow = x + (size_t)crow*IN_DIM + kc*8;

    f32x4 acc[4][4];
    #pragma unroll
    for (int i = 0; i < 4; i++)
        #pragma unroll
        for (int rt = 0; rt < 4; rt++)
            acc[i][rt] = (f32x4){0.f, 0.f, 0.f, 0.f};

    float4 rx[6];
    uint4 wcur[4], wnxt[4];

    #pragma unroll
    for (int u = 0; u < 3; u++){
        rx[2*u]   = *(const float4*)(xrow + u*32);
        rx[2*u+1] = *(const float4*)(xrow + u*32 + 4);
    }
    #pragma unroll
    for (int u = 0; u < 3; u++){
        uint4 pk;
        pk.x = pack2(rx[2*u].x,   rx[2*u].y);   pk.y = pack2(rx[2*u].z,   rx[2*u].w);
        pk.z = pack2(rx[2*u+1].x, rx[2*u+1].y); pk.w = pack2(rx[2*u+1].z, rx[2*u+1].w);
        *(uint4*)&Af[0][dls[u]] = pk;
    }
    {
        const unsigned short* p = Wf + ((size_t)(w*4)*64 + l)*8;
        #pragma unroll
        for (int i = 0; i < 4; i++) wcur[i] = *(const uint4*)(p + (size_t)i*512);
    }
    __syncthreads();

    for (int s = 0; s < 4; ++s){
        if (s < 3){
            const float* src = xrow + (s+1)*96;
            #pragma unroll
            for (int u = 0; u < 3; u++){
                rx[2*u]   = *(const float4*)(src + u*32);
                rx[2*u+1] = *(const float4*)(src + u*32 + 4);
            }
        }
        #pragma unroll
        for (int u = 0; u < 3; u++){
            int ku = s*3 + u;
            if (ku < 11){
                const unsigned short* p = Wf + ((size_t)((ku+1)*16 + w*4)*64 + l)*8;
                #pragma unroll
                for (int i = 0; i < 4; i++) wnxt[i] = *(const uint4*)(p + (size_t)i*512);
            }
            bf16x8 af[4];
            #pragma unroll
            for (int rt = 0; rt < 4; rt++)
                af[rt] = __builtin_bit_cast(bf16x8, *(const uint4*)&Af[s&1][((u*4 + rt)*64 + l)*8]);
            #pragma unroll
            for (int i = 0; i < 4; i++){
                bf16x8 bw = __builtin_bit_cast(bf16x8, wcur[i]);
                #pragma unroll
                for (int rt = 0; rt < 4; rt++)
                    acc[i][rt] = __builtin_amdgcn_mfma_f32_16x16x32_bf16(bw, af[rt], acc[i][rt], 0, 0, 0);
            }
            if (ku < 11){
                #pragma unroll
                for (int i = 0; i < 4; i++) wcur[i] = wnxt[i];
            }
        }
        if (s < 3){
            #pragma unroll
            for (int u = 0; u < 3; u++){
                uint4 pk;
                pk.x = pack2(rx[2*u].x,   rx[2*u].y);   pk.y = pack2(rx[2*u].z,   rx[2*u].w);
                pk.z = pack2(rx[2*u+1].x, rx[2*u+1].y); pk.w = pack2(rx[2*u+1].z, rx[2*u+1].w);
                *(uint4*)&Af[(s+1)&1][dls[u]] = pk;
            }
            __syncthreads();
        }
    }

    const int g = l >> 4;
    float4 cvv[4], av[4], dv[4];
    #pragma unroll
    for (int i = 0; i < 4; i++){
        int cl = i*16 + g*4;
        cvv[i] = *(const float4*)&c1v[w*64 + cl];
        av[i]  = *(const float4*)&as1[w*64 + cl];
        dv[i]  = *(const float4*)&ad1[w*64 + cl];
    }
    #pragma unroll
    for (int rt = 0; rt < 4; rt++){
        int node = n0 + rt*16 + (l & 15);
        bool ok = node < N;
        float ps = 0.f, pd = 0.f;
        #pragma unroll
        for (int i = 0; i < 4; i++){
            float h0 = acc[i][rt][0] + cvv[i].x;
            float h1v = acc[i][rt][1] + cvv[i].y;
            float h2v = acc[i][rt][2] + cvv[i].z;
            float h3v = acc[i][rt][3] + cvv[i].w;
            ps += h0*av[i].x + h1v*av[i].y + h2v*av[i].z + h3v*av[i].w;
            pd += h0*dv[i].x + h1v*dv[i].y + h2v*dv[i].z + h3v*dv[i].w;
            if (ok){
                ushort4 o = make_ushort4(f2bf(h0), f2bf(h1v), f2bf(h2v), f2bf(h3v));
                *(ushort4*)&h1[(size_t)node*C1 + w*64 + i*16 + g*4] = o;
            }
        }
        ps += __shfl_xor(ps, 16, 64); ps += __shfl_xor(ps, 32, 64);
        pd += __shfl_xor(pd, 16, 64); pd += __shfl_xor(pd, 32, 64);
        if (ok && g == 0){
            als[(size_t)node*4 + w] = ps;
            ald[(size_t)node*4 + w] = pd;
        }
    }
}

// ---------------- GEMM2 (MFMA): h2 = x2 @ W2 + fused al2 epilogue ----------------
__global__ __launch_bounds__(256) void k_gemm2_mfma(const unsigned short* __restrict__ x2,
        const unsigned short* __restrict__ Wf,
        const float* __restrict__ as2, const float* __restrict__ ad2,
        unsigned short* __restrict__ h2, float* __restrict__ als, float* __restrict__ ald, int N)
{
    __shared__ unsigned short Af[2][4*64*8];   // 2 x 4KB
    const int tid = threadIdx.x;
    const int l   = tid & 63;
    const int w   = tid >> 6;
    const int wr  = w >> 1, wc = w & 1;
    const int n0  = blockIdx.x * 64;

    const int sr  = tid >> 2;
    const int kc  = tid & 3;
    const int d0  = ((sr >> 4)*64 + kc*16 + (sr & 15))*8;
    int crow = n0 + sr; if (crow > N-1) crow = N-1;
    const unsigned short* xrow = x2 + (size_t)crow*C1 + kc*8;

    f32x4 acc[4][2];
    #pragma unroll
    for (int i = 0; i < 4; i++)
        #pragma unroll
        for (int rt = 0; rt < 2; rt++)
            acc[i][rt] = (f32x4){0.f, 0.f, 0.f, 0.f};

    uint4 p0, wcur[4], wnxt[4];
    p0 = *(const uint4*)(xrow);
    *(uint4*)&Af[0][d0] = p0;
    {
        const unsigned short* p = Wf + ((size_t)(wc*4)*64 + l)*8;
        #pragma unroll
        for (int i = 0; i < 4; i++) wcur[i] = *(const uint4*)(p + (size_t)i*512);
    }
    __syncthreads();

    for (int s = 0; s < 8; ++s){
        if (s < 7){
            p0 = *(const uint4*)(xrow + (s+1)*32);
            const unsigned short* p = Wf + ((size_t)((s+1)*8 + wc*4)*64 + l)*8;
            #pragma unroll
            for (int i = 0; i < 4; i++) wnxt[i] = *(const uint4*)(p + (size_t)i*512);
        }
        bf16x8 af[2];
        #pragma unroll
        for (int rt = 0; rt < 2; rt++)
            af[rt] = __builtin_bit_cast(bf16x8, *(const uint4*)&Af[s&1][((wr*2 + rt)*64 + l)*8]);
        #pragma unroll
        for (int i = 0; i < 4; i++){
            bf16x8 bw = __builtin_bit_cast(bf16x8, wcur[i]);
            #pragma unroll
            for (int rt = 0; rt < 2; rt++)
                acc[i][rt] = __builtin_amdgcn_mfma_f32_16x16x32_bf16(bw, af[rt], acc[i][rt], 0, 0, 0);
        }
        if (s < 7){
            *(uint4*)&Af[(s+1)&1][d0] = p0;
            __syncthreads();
            #pragma unroll
            for (int i = 0; i < 4; i++) wcur[i] = wnxt[i];
        }
    }

    const int g = l >> 4;
    float4 av[4], dv[4];
    #pragma unroll
    for (int i = 0; i < 4; i++){
        int cl = i*16 + g*4;
        av[i] = *(const float4*)&as2[wc*64 + cl];
        dv[i] = *(const float4*)&ad2[wc*64 + cl];
    }
    #pragma unroll
    for (int rt = 0; rt < 2; rt++){
        int node = n0 + wr*32 + rt*16 + (l & 15);
        bool ok = node < N;
        float ps = 0.f, pd = 0.f;
        #pragma unroll
        for (int i = 0; i < 4; i++){
            float h0 = acc[i][rt][0], h1v = acc[i][rt][1];
            float h2v = acc[i][rt][2], h3v = acc[i][rt][3];
            ps += h0*av[i].x + h1v*av[i].y + h2v*av[i].z + h3v*av[i].w;
            pd += h0*dv[i].x + h1v*dv[i].y + h2v*dv[i].z + h3v*dv[i].w;
            if (ok){
                ushort4 o = make_ushort4(f2bf(h0), f2bf(h1v), f2bf(h2v), f2bf(h3v));
                *(ushort4*)&h2[(size_t)node*C2 + wc*64 + i*16 + g*4] = o;
            }
        }
        ps += __shfl_xor(ps, 16, 64); ps += __shfl_xor(ps, 32, 64);
        pd += __shfl_xor(pd, 16, 64); pd += __shfl_xor(pd, 32, 64);
        if (ok && g == 0){
            als[(size_t)node*2 + wc] = ps;
            ald[(size_t)node*2 + wc] = pd;
        }
    }
}

// ---------------- A: edge-parallel logits e = leaky(als[src]+ald[dst]) ----------------
template<int H>
__global__ __launch_bounds__(256) void k_elogit(const int* __restrict__ colx,
        const int* __restrict__ dstx, const float* __restrict__ als,
        const float* __restrict__ ald, float* __restrict__ ep, int E)
{
    int i = blockIdx.x*256 + threadIdx.x;
    if (i >= E) return;
    int s = colx[i], d = dstx[i];
    if constexpr (H == 4){
        float4 a = *(const float4*)&als[(size_t)s*4];
        float4 b = *(const float4*)&ald[(size_t)d*4];
        float4 e;
        e.x = a.x + b.x; e.x = fmaxf(e.x, 0.2f*e.x);
        e.y = a.y + b.y; e.y = fmaxf(e.y, 0.2f*e.y);
        e.z = a.z + b.z; e.z = fmaxf(e.z, 0.2f*e.z);
        e.w = a.w + b.w; e.w = fmaxf(e.w, 0.2f*e.w);
        *(float4*)&ep[(size_t)i*4] = e;
    } else {
        float2 a = *(const float2*)&als[(size_t)s*2];
        float2 b = *(const float2*)&ald[(size_t)d*2];
        float2 e;
        e.x = a.x + b.x; e.x = fmaxf(e.x, 0.2f*e.x);
        e.y = a.y + b.y; e.y = fmaxf(e.y, 0.2f*e.y);
        *(float2*)&ep[(size_t)i*2] = e;
    }
}

// dstx rebuild: position-parallel (dstx[p] = node owning position p)
template<int H>
__global__ __launch_bounds__(256) void k_dstfill(const int* __restrict__ rowptr,
        const int* __restrict__ deg, int* __restrict__ dstx, int N)
{
    int i = blockIdx.x*256 + threadIdx.x;
    if (i >= N) return;
    int base = rowptr[i], cnt = deg[i];
    for (int j = 0; j < cnt; j++) dstx[base + j] = i;
}

// ---------------- B: thread per (node,head) segment softmax; ep <- p (in place) -------
template<int H>
__global__ __launch_bounds__(256) void k_segsm(const int* __restrict__ rowptr,
        const int* __restrict__ deg,
        const float* __restrict__ als, const float* __restrict__ ald,
        float* __restrict__ ep, float* __restrict__ den, float* __restrict__ pSelf, int NH)
{
    int t = blockIdx.x*256 + threadIdx.x;
    if (t >= NH) return;
    int node = t / H;
    int head = t - node*H;
    int base = rowptr[node];
    int cnt  = deg[node];
    float es = als[t] + ald[t];
    es = fmaxf(es, 0.2f*es);
    float m = es;
    for (int j = 0; j < cnt; j++)
        m = fmaxf(m, ep[(size_t)(base + j)*H + head]);
    float ps = __expf(es - m);
    float dn = ps;
    for (int j = 0; j < cnt; j++){
        size_t idx = (size_t)(base + j)*H + head;
        float p = __expf(ep[idx] - m);
        ep[idx] = p;
        dn += p;
    }
    den[t]   = dn;
    pSelf[t] = ps;
}

// ---------------- C: wave-per-node weighted gather-sum (no softmax in loop) ----------
template<int H, int CPL, int LAYER>
__global__ __launch_bounds__(256) void k_gat(const unsigned short* __restrict__ hlin,
        const float* __restrict__ ep, const float* __restrict__ den, const float* __restrict__ pSelf,
        const int* __restrict__ rowptr, const int* __restrict__ deg, const int* __restrict__ colx,
        const float* __restrict__ bias, const float* __restrict__ gate,
        unsigned short* __restrict__ out_bf, float* __restrict__ out_f, int N)
{
    constexpr int C = H*64;
    constexpr uint32 RB = C*2;               // bf16 row bytes
    int lane = threadIdx.x & 63, wid = threadIdx.x >> 6;
    int n = blockIdx.x*4 + wid;
    if (n >= N) return;
    const int c0 = lane*CPL;
    const int head = c0 >> 6;
    const int base = rowptr[n];
    const int cnt  = deg[n];
    const char* hbase = (const char*)hlin + (uint32)c0*2;

    float acc[CPL];
    {
        float psf = pSelf[(uint32)n*H + head];
        if constexpr (CPL == 4){
            ushort4 v = *(const ushort4*)(hbase + (size_t)(uint32)n*RB);
            acc[0] = psf*bf2f(v.x); acc[1] = psf*bf2f(v.y);
            acc[2] = psf*bf2f(v.z); acc[3] = psf*bf2f(v.w);
        } else {
            uint32 v = *(const uint32*)(hbase + (size_t)(uint32)n*RB);
            acc[0] = psf*bf2f((unsigned short)(v & 0xffff));
            acc[1] = psf*bf2f((unsigned short)(v >> 16));
        }
    }
    for (int i = 0; i < cnt; i += 4){
        int idx[4], sk[4];
        #pragma unroll
        for (int k = 0; k < 4; k++){
            int ii = i + k; if (ii > cnt-1) ii = cnt-1;
            idx[k] = base + ii;
        }
        #pragma unroll
        for (int k = 0; k < 4; k++) sk[k] = colx[idx[k]];
        float pk[4];
        #pragma unroll
        for (int k = 0; k < 4; k++){
            float pv = ep[(size_t)(uint32)idx[k]*H + head];
            pk[k] = (i + k < cnt) ? pv : 0.f;
        }
        if constexpr (CPL == 4){
            ushort4 h4[4];
            #pragma unroll
            for (int k = 0; k < 4; k++) h4[k] = *(const ushort4*)(hbase + (size_t)(uint32)sk[k]*RB);
            #pragma unroll
            for (int k = 0; k < 4; k++){
                acc[0] += pk[k]*bf2f(h4[k].x);
                acc[1] += pk[k]*bf2f(h4[k].y);
                acc[2] += pk[k]*bf2f(h4[k].z);
                acc[3] += pk[k]*bf2f(h4[k].w);
            }
        } else {
            uint32 h2v[4];
            #pragma unroll
            for (int k = 0; k < 4; k++) h2v[k] = *(const uint32*)(hbase + (size_t)(uint32)sk[k]*RB);
            #pragma unroll
            for (int k = 0; k < 4; k++){
                acc[0] += pk[k]*bf2f((unsigned short)(h2v[k] & 0xffff));
                acc[1] += pk[k]*bf2f((unsigned short)(h2v[k] >> 16));
            }
        }
    }

    float inv = 1.f/(den[(uint32)n*H + head] + 1e-16f);
    if constexpr (LAYER == 1){
        unsigned short o[CPL];
        #pragma unroll
        for (int j = 0; j < CPL; j++){
            float r = acc[j]*inv + bias[c0 + j];
            r = (r > 0.f) ? r : (__expf(r) - 1.f);   // elu
            o[j] = f2bf(r);
        }
        if constexpr (CPL == 4){
            ushort4 ov; ov.x = o[0]; ov.y = o[1]; ov.z = o[2]; ov.w = o[3];
            *(ushort4*)&out_bf[(size_t)n*C + c0] = ov;
        }
    } else {
        float o[CPL];
        #pragma unroll
        for (int j = 0; j < CPL; j++){
            float r = acc[j]*inv + bias[c0 + j];
            r = (r > 0.f) ? r : (__expf(r) - 1.f);   // elu
            o[j] = r*gate[(c0 + j) & 63];
        }
        if constexpr (CPL == 2){
            *(float2*)&out_f[(size_t)n*C + c0] = make_float2(o[0], o[1]);
        }
    }
}

// ---------------- attn MLP via MFMA: attn = sigmoid(relu(outh@aw1+ab1)@aw2+ab2) -------
__global__ __launch_bounds__(256) void k_attn_mfma(const float* __restrict__ outh,
        const unsigned short* __restrict__ Wfa, const float* __restrict__ ab1,
        const float* __restrict__ aw2, const float* __restrict__ ab2,
        float* __restrict__ attn, int N)
{
    __shared__ unsigned short Af[4*8*64*8];   // 32 KB
    const int tid = threadIdx.x;
    const int l   = tid & 63;
    const int w   = tid >> 6;
    const int n0  = blockIdx.x * 128;

    const int r  = tid >> 1;
    const int kh = tid & 1;
    const int rt8 = r >> 4, rr = r & 15;
    int crow = n0 + r; if (crow > N-1) crow = N-1;
    const float* src = outh + (size_t)crow*C2 + kh*16;
    #pragma unroll
    for (int s = 0; s < 4; s++){
        float4 a = *(const float4*)(src + s*32 + 0);
        float4 b = *(const float4*)(src + s*32 + 4);
        float4 c = *(const float4*)(src + s*32 + 8);
        float4 d = *(const float4*)(src + s*32 + 12);
        uint4 u0, u1;
        u0.x = pack2(a.x, a.y); u0.y = pack2(a.z, a.w);
        u0.z = pack2(b.x, b.y); u0.w = pack2(b.z, b.w);
        u1.x = pack2(c.x, c.y); u1.y = pack2(c.z, c.w);
        u1.z = pack2(d.x, d.y); u1.w = pack2(d.z, d.w);
        int d0 = ((s*8 + rt8)*64 + (kh*2)*16 + rr)*8;
        *(uint4*)&Af[d0]       = u0;
        *(uint4*)&Af[d0 + 128] = u1;
    }
    __syncthreads();

    f32x4 acc[4][2];
    #pragma unroll
    for (int i = 0; i < 4; i++)
        #pragma unroll
        for (int rt = 0; rt < 2; rt++)
            acc[i][rt] = (f32x4){0.f, 0.f, 0.f, 0.f};

    #pragma unroll
    for (int s = 0; s < 4; s++){
        bf16x8 af[2];
        #pragma unroll
        for (int rt = 0; rt < 2; rt++)
            af[rt] = __builtin_bit_cast(bf16x8, *(const uint4*)&Af[((s*8 + w*2 + rt)*64 + l)*8]);
        #pragma unroll
        for (int i = 0; i < 4; i++){
            bf16x8 bw = __builtin_bit_cast(bf16x8, *(const uint4*)&Wfa[((size_t)(s*4 + i)*64 + l)*8]);
            #pragma unroll
            for (int rt = 0; rt < 2; rt++)
                acc[i][rt] = __builtin_amdgcn_mfma_f32_16x16x32_bf16(bw, af[rt], acc[i][rt], 0, 0, 0);
        }
    }

    const int g = l >> 4;
    float4 abv[4], awv[4];
    #pragma unroll
    for (int i = 0; i < 4; i++){
        abv[i] = *(const float4*)&ab1[i*16 + g*4];
        awv[i] = *(const float4*)&aw2[i*16 + g*4];
    }
    float b2v = ab2[0];
    #pragma unroll
    for (int rt = 0; rt < 2; rt++){
        int node = n0 + (w*2 + rt)*16 + (l & 15);
        float part = 0.f;
        #pragma unroll
        for (int i = 0; i < 4; i++){
            float v0 = fmaxf(acc[i][rt][0] + abv[i].x, 0.f);
            float v1 = fmaxf(acc[i][rt][1] + abv[i].y, 0.f);
            float v2 = fmaxf(acc[i][rt][2] + abv[i].z, 0.f);
            float v3 = fmaxf(acc[i][rt][3] + abv[i].w, 0.f);
            part += v0*awv[i].x + v1*awv[i].y + v2*awv[i].z + v3*awv[i].w;
        }
        part += __shfl_xor(part, 16, 64);
        part += __shfl_xor(part, 32, 64);
        if (g == 0 && node < N)
            attn[node] = 1.f/(1.f + __expf(-(part + b2v)));
    }
}

extern "C" void kernel_launch(void* const* d_in, const int* in_sizes, int n_in,
                              void* d_out, int out_size, void* d_ws, size_t ws_size,
                              hipStream_t stream)
{
    const float* x    = (const float*)d_in[0];
    const int*   ei   = (const int*)  d_in[1];
    const float* pad  = (const float*)d_in[2];
    const float* W1   = (const float*)d_in[3];
    const float* as1  = (const float*)d_in[4];
    const float* ad1  = (const float*)d_in[5];
    const float* b1   = (const float*)d_in[6];
    const float* W2   = (const float*)d_in[7];
    const float* as2  = (const float*)d_in[8];
    const float* ad2  = (const float*)d_in[9];
    const float* b2   = (const float*)d_in[10];
    const float* aw1  = (const float*)d_in[11];
    const float* ab1  = (const float*)d_in[12];
    const float* aw2  = (const float*)d_in[13];
    const float* ab2  = (const float*)d_in[14];
    const float* gw   = (const float*)d_in[15];
    const float* gb   = (const float*)d_in[16];

    const int N = in_sizes[0] / IN_DIM;
    const int E = in_sizes[1] / 2;

    float* outh    = (float*)d_out;
    float* outattn = outh + (size_t)N*C2;

    char* w = (char*)d_ws;
    auto alloc = [&](size_t bytes)->char*{
        char* p = w;
        w += (bytes + 255) & ~(size_t)255;
        return p;
    };
    unsigned short* h1  = (unsigned short*)alloc((size_t)N*C1*2);
    unsigned short* x2  = (unsigned short*)alloc((size_t)N*C1*2);
    unsigned short* h2  = (unsigned short*)alloc((size_t)N*C2*2);
    float* als1 = (float*)alloc((size_t)N*4*4);
    float* ald1 = (float*)alloc((size_t)N*4*4);
    float* als2 = (float*)alloc((size_t)N*2*4);
    float* ald2 = (float*)alloc((size_t)N*2*4);
    int* deg    = (int*)alloc((size_t)N*4);
    int* cur    = (int*)alloc((size_t)N*4);
    int* rowptr = (int*)alloc((size_t)(N+1)*4);
    int* colx   = (int*)alloc((size_t)E*4);
    int* dstx   = (int*)alloc((size_t)E*4);
    int* total  = (int*)alloc(256);
    unsigned short* Wf1 = (unsigned short*)alloc((size_t)12*16*64*8*2);
    unsigned short* Wf2 = (unsigned short*)alloc((size_t)8*8*64*8*2);
    unsigned short* Wfa = (unsigned short*)alloc((size_t)4*4*64*8*2);
    float* c1v  = (float*)alloc(C1*4);
    float* gate = (float*)alloc(HID*4);

    // Lifetime-based aliases (no new footprint):
    float* ep1    = (float*)h2;                                   // E*4 floats
    float* den1   = (float*)((char*)h2 + (size_t)E*16);           // N*4 floats
    float* pSelf1 = (float*)((char*)h2 + (size_t)E*16 + (size_t)N*16);
    float* ep2    = (float*)x2;                                   // E*2 floats
    float* den2   = (float*)((char*)x2 + (size_t)E*8);            // N*2 floats
    float* pSelf2 = (float*)((char*)x2 + (size_t)E*8 + (size_t)N*8);

    const int nbN = (N + 255)/256;
    const int nbE = (E + 255)/256;
    const int nbW = (N + 3)/4;        // wave-per-node kernels
    const int nbG = (N + 63)/64;      // gemm row blocks (64-row tiles)
    const int nbA = (N + 127)/128;    // attn-MLP row blocks

    // weight swizzles + constants (independent of CSR)
    k_cvtW <<<(192+3)/4, 256, 0, stream>>>(W1, Wf1, C1, 16, 192);
    k_cvtW <<<(64+3)/4,  256, 0, stream>>>(W2, Wf2, C2, 8, 64);
    k_cvtW <<<(16+3)/4,  256, 0, stream>>>(aw1, Wfa, HID, 4, 16);
    k_prep <<<1, 256, 0, stream>>>(W1, pad, gw, gb, c1v, gate);

    // CSR by destination (atomic-range, no prefix scan)
    k_zero   <<<nbN, 256, 0, stream>>>(deg, cur, total, N);
    k_hist   <<<nbE, 256, 0, stream>>>(ei, deg, E);
    k_range  <<<nbN, 256, 0, stream>>>(deg, rowptr, total, N);
    k_scatter<<<nbE, 256, 0, stream>>>(ei, rowptr, cur, colx, E);
    k_dstfill<4><<<nbN, 256, 0, stream>>>(rowptr, deg, dstx, N);

    // ---- layer 1 ----
    k_gemm1_mfma<<<nbG, 256, 0, stream>>>(x, Wf1, c1v, as1, ad1, h1, als1, ald1, N);
    k_elogit<4><<<nbE, 256, 0, stream>>>(colx, dstx, als1, ald1, ep1, E);
    k_segsm<4> <<<(N*4 + 255)/256, 256, 0, stream>>>(rowptr, deg, als1, ald1, ep1, den1, pSelf1, N*4);
    k_gat<4,4,1><<<nbW, 256, 0, stream>>>(h1, ep1, den1, pSelf1, rowptr, deg, colx, b1,
                                          nullptr, x2, nullptr, N);

    // ---- layer 2 ----
    k_gemm2_mfma<<<nbG, 256, 0, stream>>>(x2, Wf2, as2, ad2, h2, als2, ald2, N);
    k_elogit<2><<<nbE, 256, 0, stream>>>(colx, dstx, als2, ald2, ep2, E);
    k_segsm<2> <<<(N*2 + 255)/256, 256, 0, stream>>>(rowptr, deg, als2, ald2, ep2, den2, pSelf2, N*2);
    k_gat<2,2,2><<<nbW, 256, 0, stream>>>(h2, ep2, den2, pSelf2, rowptr, deg, colx, b2,
                                          gate, nullptr, outh, N);

    // ---- attention-score MLP (MFMA) ----
    k_attn_mfma<<<nbA, 256, 0, stream>>>(outh, Wfa, ab1, aw2, ab2, outattn, N);
}

// Round 17
// 287.310 us; speedup vs baseline: 1.2142x; 1.0467x over previous
//
#include <hip/hip_runtime.h>
#include <hip/hip_bf16.h>
#include <stdint.h>

#define IN_DIM 384
#define HID 64
#define C1 256   // 4 heads * 64
#define C2 128   // 2 heads * 64

typedef unsigned int uint32;
typedef __bf16 bf16x8 __attribute__((ext_vector_type(8)));
typedef float f32x4 __attribute__((ext_vector_type(4)));
typedef const __attribute__((address_space(1))) void* gas_ptr;
typedef __attribute__((address_space(3))) void* las_ptr;

static __device__ __forceinline__ float bf2f(unsigned short u){
    return __uint_as_float(((uint32)u) << 16);
}
static __device__ __forceinline__ unsigned short f2bf(float x){
    uint32 u = __float_as_uint(x);
    return (unsigned short)((u + 0x7FFFu + ((u >> 16) & 1u)) >> 16);
}
static __device__ __forceinline__ uint32 pack2(float a, float b){
    return (uint32)f2bf(a) | ((uint32)f2bf(b) << 16);
}

// ---------------- CSR build (round-9 scan form) ----------------
__global__ void k_zero(int* deg, int* cur, int N){
    int i = blockIdx.x*256 + threadIdx.x;
    if (i < N){ deg[i] = 0; cur[i] = 0; }
}
__global__ void k_hist(const int* __restrict__ ei, int* deg, int E){
    int i = blockIdx.x*256 + threadIdx.x;
    if (i < E) atomicAdd(&deg[ei[E + i]], 1);
}
__global__ void k_scan1(const int* __restrict__ deg, int* rowptr, int* part, int N){
    __shared__ int s[256];
    int tid = threadIdx.x;
    int i = blockIdx.x*256 + tid;
    int v = (i < N) ? deg[i] : 0;
    s[tid] = v; __syncthreads();
    for (int off = 1; off < 256; off <<= 1){
        int t = (tid >= off) ? s[tid - off] : 0;
        __syncthreads();
        s[tid] += t;
        __syncthreads();
    }
    if (i < N) rowptr[i] = s[tid] - v;
    if (tid == 255) part[blockIdx.x] = s[tid];
}
__global__ void k_scan2(int* part, int nb){
    __shared__ int s[512];
    int tid = threadIdx.x;
    int v = (tid < nb) ? part[tid] : 0;
    s[tid] = v; __syncthreads();
    for (int off = 1; off < 512; off <<= 1){
        int t = (tid >= off) ? s[tid - off] : 0;
        __syncthreads();
        s[tid] += t;
        __syncthreads();
    }
    if (tid < nb) part[tid] = s[tid] - v;
}
__global__ void k_scan3(int* rowptr, const int* __restrict__ part, int N, int E){
    int i = blockIdx.x*256 + threadIdx.x;
    if (i < N) rowptr[i] += part[blockIdx.x];
    if (i == 0) rowptr[N] = E;
}
__global__ void k_scatter(const int* __restrict__ ei, const int* __restrict__ rowptr,
                          int* cur, int* colx, int* dstx, int E){
    int i = blockIdx.x*256 + threadIdx.x;
    if (i < E){
        int d = ei[E + i];
        int pos = atomicAdd(&cur[d], 1);
        int p = rowptr[d] + pos;
        colx[p] = ei[i];
        dstx[p] = d;
    }
}

// ---------------- weight pre-swizzle: contiguous-k fragment order ----------------
__global__ __launch_bounds__(256) void k_cvtW(const float* __restrict__ W,
        unsigned short* __restrict__ Wf, int ncol, int ntiles, int nunits){
    int unit = blockIdx.x*4 + (threadIdx.x >> 6);
    if (unit >= nunits) return;
    int l = threadIdx.x & 63;
    int s = unit / ntiles, ct = unit % ntiles;
    int col = ct*16 + (l & 15);
    int g = l >> 4;
    unsigned short o[8];
    #pragma unroll
    for (int j = 0; j < 8; j++){
        int k = s*32 + g*8 + j;
        o[j] = f2bf(W[(size_t)k*ncol + col]);
    }
    ushort4* dst = (ushort4*)&Wf[((size_t)unit*64 + l)*8];
    dst[0] = make_ushort4(o[0], o[1], o[2], o[3]);
    dst[1] = make_ushort4(o[4], o[5], o[6], o[7]);
}

// ---------------- constant precompute: pad bias, emotion gate ----------
__global__ __launch_bounds__(256) void k_prep(const float* __restrict__ W1,
        const float* __restrict__ pad, const float* __restrict__ gw, const float* __restrict__ gb,
        float* __restrict__ c1v, float* __restrict__ gate){
    int tid = threadIdx.x;
    c1v[tid] = pad[0]*W1[(size_t)(IN_DIM+0)*C1 + tid]
             + pad[1]*W1[(size_t)(IN_DIM+1)*C1 + tid]
             + pad[2]*W1[(size_t)(IN_DIM+2)*C1 + tid];
    if (tid < HID){
        float g = pad[0]*gw[0*HID + tid] + pad[1]*gw[1*HID + tid] + pad[2]*gw[2*HID + tid] + gb[tid];
        gate[tid] = 1.f/(1.f + __expf(-g));
    }
}

// ---------------- GEMM1 (MFMA): h1 = [x|pad]@W1 + fused al1 epilogue ----------------
// 32 rows x 256 cols per block, 4 waves (wave = head). Staging via
// __builtin_amdgcn_global_load_lds width=16 (fire-and-forget DMA, no VGPR round-trip):
// LDS = fp32 [32][384] linear, fragment-read bank spread via SOURCE-address XOR swizzle
// ((row&3)<<5, m173 pattern). ONE barrier, 12 k-units MFMA, in-register f32->bf16.
__global__ __launch_bounds__(256) void k_gemm1_mfma(const float* __restrict__ x,
        const unsigned short* __restrict__ Wf, const float* __restrict__ c1v,
        const float* __restrict__ as1, const float* __restrict__ ad1,
        unsigned short* __restrict__ h1, float* __restrict__ als, float* __restrict__ ald, int N)
{
    __shared__ float Afs[32*IN_DIM];   // 48 KB fp32
    const int tid = threadIdx.x;
    const int l   = tid & 63;
    const int w   = tid >> 6;
    const int n0  = blockIdx.x * 32;

    // ---- DMA staging: 12 x global_load_lds(16B) per thread ----
    const char* xg = (const char*)(x + (size_t)n0*IN_DIM);
    #pragma unroll
    for (int it = 0; it < 12; ++it){
        int chunk = it*256 + tid;              // 16B chunk index in [0,3072)
        int row   = chunk/96;
        uint32 b  = (uint32)chunk*16;
        uint32 s  = ((uint32)(row & 3)) << 5;  // involutive source swizzle
        const char* src;
        if (n0 + row < N) src = xg + (b ^ s);
        else              src = (const char*)x;          // safe dummy
        uint32 ldsbase = (uint32)(it*256 + (tid & 0xFFC0))*16;   // wave-uniform
        __builtin_amdgcn_global_load_lds((gas_ptr)src,
                                         (las_ptr)((char*)Afs + ldsbase), 16, 0, 0);
    }

    f32x4 acc[4][2];
    #pragma unroll
    for (int i = 0; i < 4; i++)
        #pragma unroll
        for (int rt = 0; rt < 2; rt++)
            acc[i][rt] = (f32x4){0.f, 0.f, 0.f, 0.f};

    uint4 wcur[4], wnxt[4];
    {
        const unsigned short* p = Wf + ((size_t)(w*4)*64 + l)*8;
        #pragma unroll
        for (int i = 0; i < 4; i++) wcur[i] = *(const uint4*)(p + (size_t)i*512);
    }
    __syncthreads();

    // fragment base addrs (swizzled): row = rt*16 + (l&15); k-slice (l>>4)*8 floats
    const uint32 row0 = (uint32)(l & 15);
    const uint32 row1 = row0 + 16;
    const uint32 ad0  = (row0*1536 + ((uint32)(l >> 4))*32) ^ ((row0 & 3) << 5);
    const uint32 ad1b = (row1*1536 + ((uint32)(l >> 4))*32) ^ ((row1 & 3) << 5);

    for (int ku = 0; ku < 12; ++ku){
        if (ku < 11){
            const unsigned short* p = Wf + ((size_t)((ku+1)*16 + w*4)*64 + l)*8;
            #pragma unroll
            for (int i = 0; i < 4; i++) wnxt[i] = *(const uint4*)(p + (size_t)i*512);
        }
        bf16x8 af[2];
        {
            float4 fa = *(const float4*)((const char*)Afs + ad0 + ku*128);
            float4 fb = *(const float4*)((const char*)Afs + ad0 + ku*128 + 16);
            uint4 u; u.x = pack2(fa.x, fa.y); u.y = pack2(fa.z, fa.w);
            u.z = pack2(fb.x, fb.y); u.w = pack2(fb.z, fb.w);
            af[0] = __builtin_bit_cast(bf16x8, u);
        }
        {
            float4 fa = *(const float4*)((const char*)Afs + ad1b + ku*128);
            float4 fb = *(const float4*)((const char*)Afs + ad1b + ku*128 + 16);
            uint4 u; u.x = pack2(fa.x, fa.y); u.y = pack2(fa.z, fa.w);
            u.z = pack2(fb.x, fb.y); u.w = pack2(fb.z, fb.w);
            af[1] = __builtin_bit_cast(bf16x8, u);
        }
        #pragma unroll
        for (int i = 0; i < 4; i++){
            bf16x8 bw = __builtin_bit_cast(bf16x8, wcur[i]);
            #pragma unroll
            for (int rt = 0; rt < 2; rt++)
                acc[i][rt] = __builtin_amdgcn_mfma_f32_16x16x32_bf16(bw, af[rt], acc[i][rt], 0, 0, 0);
        }
        if (ku < 11){
            #pragma unroll
            for (int i = 0; i < 4; i++) wcur[i] = wnxt[i];
        }
    }

    const int g = l >> 4;
    float4 cvv[4], av[4], dv[4];
    #pragma unroll
    for (int i = 0; i < 4; i++){
        int cl = i*16 + g*4;
        cvv[i] = *(const float4*)&c1v[w*64 + cl];
        av[i]  = *(const float4*)&as1[w*64 + cl];
        dv[i]  = *(const float4*)&ad1[w*64 + cl];
    }
    #pragma unroll
    for (int rt = 0; rt < 2; rt++){
        int node = n0 + rt*16 + (l & 15);
        bool ok = node < N;
        float ps = 0.f, pd = 0.f;
        #pragma unroll
        for (int i = 0; i < 4; i++){
            float h0 = acc[i][rt][0] + cvv[i].x;
            float h1v = acc[i][rt][1] + cvv[i].y;
            float h2v = acc[i][rt][2] + cvv[i].z;
            float h3v = acc[i][rt][3] + cvv[i].w;
            ps += h0*av[i].x + h1v*av[i].y + h2v*av[i].z + h3v*av[i].w;
            pd += h0*dv[i].x + h1v*dv[i].y + h2v*dv[i].z + h3v*dv[i].w;
            if (ok){
                ushort4 o = make_ushort4(f2bf(h0), f2bf(h1v), f2bf(h2v), f2bf(h3v));
                *(ushort4*)&h1[(size_t)node*C1 + w*64 + i*16 + g*4] = o;
            }
        }
        ps += __shfl_xor(ps, 16, 64); ps += __shfl_xor(ps, 32, 64);
        pd += __shfl_xor(pd, 16, 64); pd += __shfl_xor(pd, 32, 64);
        if (ok && g == 0){
            als[(size_t)node*4 + w] = ps;
            ald[(size_t)node*4 + w] = pd;
        }
    }
}

// ---------------- GEMM2 (MFMA): h2 = x2 @ W2 + fused al2 epilogue (round-9) -------
__global__ __launch_bounds__(256) void k_gemm2_mfma(const unsigned short* __restrict__ x2,
        const unsigned short* __restrict__ Wf,
        const float* __restrict__ as2, const float* __restrict__ ad2,
        unsigned short* __restrict__ h2, float* __restrict__ als, float* __restrict__ ald, int N)
{
    __shared__ unsigned short Af[2][4*64*8];   // 2 x 4KB
    const int tid = threadIdx.x;
    const int l   = tid & 63;
    const int w   = tid >> 6;
    const int wr  = w >> 1, wc = w & 1;
    const int n0  = blockIdx.x * 64;

    const int sr  = tid >> 2;
    const int kc  = tid & 3;
    const int d0  = ((sr >> 4)*64 + kc*16 + (sr & 15))*8;
    int crow = n0 + sr; if (crow > N-1) crow = N-1;
    const unsigned short* xrow = x2 + (size_t)crow*C1 + kc*8;

    f32x4 acc[4][2];
    #pragma unroll
    for (int i = 0; i < 4; i++)
        #pragma unroll
        for (int rt = 0; rt < 2; rt++)
            acc[i][rt] = (f32x4){0.f, 0.f, 0.f, 0.f};

    uint4 p0, wcur[4], wnxt[4];
    p0 = *(const uint4*)(xrow);
    *(uint4*)&Af[0][d0] = p0;
    {
        const unsigned short* p = Wf + ((size_t)(wc*4)*64 + l)*8;
        #pragma unroll
        for (int i = 0; i < 4; i++) wcur[i] = *(const uint4*)(p + (size_t)i*512);
    }
    __syncthreads();

    for (int s = 0; s < 8; ++s){
        if (s < 7){
            p0 = *(const uint4*)(xrow + (s+1)*32);
            const unsigned short* p = Wf + ((size_t)((s+1)*8 + wc*4)*64 + l)*8;
            #pragma unroll
            for (int i = 0; i < 4; i++) wnxt[i] = *(const uint4*)(p + (size_t)i*512);
        }
        bf16x8 af[2];
        #pragma unroll
        for (int rt = 0; rt < 2; rt++)
            af[rt] = __builtin_bit_cast(bf16x8, *(const uint4*)&Af[s&1][((wr*2 + rt)*64 + l)*8]);
        #pragma unroll
        for (int i = 0; i < 4; i++){
            bf16x8 bw = __builtin_bit_cast(bf16x8, wcur[i]);
            #pragma unroll
            for (int rt = 0; rt < 2; rt++)
                acc[i][rt] = __builtin_amdgcn_mfma_f32_16x16x32_bf16(bw, af[rt], acc[i][rt], 0, 0, 0);
        }
        if (s < 7){
            *(uint4*)&Af[(s+1)&1][d0] = p0;
            __syncthreads();
            #pragma unroll
            for (int i = 0; i < 4; i++) wcur[i] = wnxt[i];
        }
    }

    const int g = l >> 4;
    float4 av[4], dv[4];
    #pragma unroll
    for (int i = 0; i < 4; i++){
        int cl = i*16 + g*4;
        av[i] = *(const float4*)&as2[wc*64 + cl];
        dv[i] = *(const float4*)&ad2[wc*64 + cl];
    }
    #pragma unroll
    for (int rt = 0; rt < 2; rt++){
        int node = n0 + wr*32 + rt*16 + (l & 15);
        bool ok = node < N;
        float ps = 0.f, pd = 0.f;
        #pragma unroll
        for (int i = 0; i < 4; i++){
            float h0 = acc[i][rt][0], h1v = acc[i][rt][1];
            float h2v = acc[i][rt][2], h3v = acc[i][rt][3];
            ps += h0*av[i].x + h1v*av[i].y + h2v*av[i].z + h3v*av[i].w;
            pd += h0*dv[i].x + h1v*dv[i].y + h2v*dv[i].z + h3v*dv[i].w;
            if (ok){
                ushort4 o = make_ushort4(f2bf(h0), f2bf(h1v), f2bf(h2v), f2bf(h3v));
                *(ushort4*)&h2[(size_t)node*C2 + wc*64 + i*16 + g*4] = o;
            }
        }
        ps += __shfl_xor(ps, 16, 64); ps += __shfl_xor(ps, 32, 64);
        pd += __shfl_xor(pd, 16, 64); pd += __shfl_xor(pd, 32, 64);
        if (ok && g == 0){
            als[(size_t)node*2 + wc] = ps;
            ald[(size_t)node*2 + wc] = pd;
        }
    }
}

// ---------------- A: edge-parallel logits e = leaky(als[src]+ald[dst]) ----------------
template<int H>
__global__ __launch_bounds__(256) void k_elogit(const int* __restrict__ colx,
        const int* __restrict__ dstx, const float* __restrict__ als,
        const float* __restrict__ ald, float* __restrict__ ep, int E)
{
    int i = blockIdx.x*256 + threadIdx.x;
    if (i >= E) return;
    int s = colx[i], d = dstx[i];
    if constexpr (H == 4){
        float4 a = *(const float4*)&als[(size_t)s*4];
        float4 b = *(const float4*)&ald[(size_t)d*4];
        float4 e;
        e.x = a.x + b.x; e.x = fmaxf(e.x, 0.2f*e.x);
        e.y = a.y + b.y; e.y = fmaxf(e.y, 0.2f*e.y);
        e.z = a.z + b.z; e.z = fmaxf(e.z, 0.2f*e.z);
        e.w = a.w + b.w; e.w = fmaxf(e.w, 0.2f*e.w);
        *(float4*)&ep[(size_t)i*4] = e;
    } else {
        float2 a = *(const float2*)&als[(size_t)s*2];
        float2 b = *(const float2*)&ald[(size_t)d*2];
        float2 e;
        e.x = a.x + b.x; e.x = fmaxf(e.x, 0.2f*e.x);
        e.y = a.y + b.y; e.y = fmaxf(e.y, 0.2f*e.y);
        *(float2*)&ep[(size_t)i*2] = e;
    }
}

// ---------------- B: thread per (node,head) segment softmax; ep <- p (in place) -------
template<int H>
__global__ __launch_bounds__(256) void k_segsm(const int* __restrict__ rowptr,
        const float* __restrict__ als, const float* __restrict__ ald,
        float* __restrict__ ep, float* __restrict__ den, float* __restrict__ pSelf, int NH)
{
    int t = blockIdx.x*256 + threadIdx.x;
    if (t >= NH) return;
    int node = t / H;
    int head = t - node*H;
    int base = rowptr[node];
    int cnt  = rowptr[node+1] - base;
    float es = als[t] + ald[t];
    es = fmaxf(es, 0.2f*es);
    float m = es;
    for (int j = 0; j < cnt; j++)
        m = fmaxf(m, ep[(size_t)(base + j)*H + head]);
    float ps = __expf(es - m);
    float dn = ps;
    for (int j = 0; j < cnt; j++){
        size_t idx = (size_t)(base + j)*H + head;
        float p = __expf(ep[idx] - m);
        ep[idx] = p;
        dn += p;
    }
    den[t]   = dn;
    pSelf[t] = ps;
}

// ---------------- C: wave-per-node weighted gather-sum (no softmax in loop) ----------
template<int H, int CPL, int LAYER>
__global__ __launch_bounds__(256) void k_gat(const unsigned short* __restrict__ hlin,
        const float* __restrict__ ep, const float* __restrict__ den, const float* __restrict__ pSelf,
        const int* __restrict__ rowptr, const int* __restrict__ colx,
        const float* __restrict__ bias, const float* __restrict__ gate,
        unsigned short* __restrict__ out_bf, float* __restrict__ out_f, int N)
{
    constexpr int C = H*64;
    constexpr uint32 RB = C*2;               // bf16 row bytes
    int lane = threadIdx.x & 63, wid = threadIdx.x >> 6;
    int n = blockIdx.x*4 + wid;
    if (n >= N) return;
    const int c0 = lane*CPL;
    const int head = c0 >> 6;
    const int base = rowptr[n];
    const int cnt  = rowptr[n+1] - base;
    const char* hbase = (const char*)hlin + (uint32)c0*2;

    float acc[CPL];
    {
        float psf = pSelf[(uint32)n*H + head];
        if constexpr (CPL == 4){
            ushort4 v = *(const ushort4*)(hbase + (size_t)(uint32)n*RB);
            acc[0] = psf*bf2f(v.x); acc[1] = psf*bf2f(v.y);
            acc[2] = psf*bf2f(v.z); acc[3] = psf*bf2f(v.w);
        } else {
            uint32 v = *(const uint32*)(hbase + (size_t)(uint32)n*RB);
            acc[0] = psf*bf2f((unsigned short)(v & 0xffff));
            acc[1] = psf*bf2f((unsigned short)(v >> 16));
        }
    }
    for (int i = 0; i < cnt; i += 4){
        int idx[4], sk[4];
        #pragma unroll
        for (int k = 0; k < 4; k++){
            int ii = i + k; if (ii > cnt-1) ii = cnt-1;
            idx[k] = base + ii;
        }
        #pragma unroll
        for (int k = 0; k < 4; k++) sk[k] = colx[idx[k]];
        float pk[4];
        #pragma unroll
        for (int k = 0; k < 4; k++){
            float pv = ep[(size_t)(uint32)idx[k]*H + head];
            pk[k] = (i + k < cnt) ? pv : 0.f;
        }
        if constexpr (CPL == 4){
            ushort4 h4[4];
            #pragma unroll
            for (int k = 0; k < 4; k++) h4[k] = *(const ushort4*)(hbase + (size_t)(uint32)sk[k]*RB);
            #pragma unroll
            for (int k = 0; k < 4; k++){
                acc[0] += pk[k]*bf2f(h4[k].x);
                acc[1] += pk[k]*bf2f(h4[k].y);
                acc[2] += pk[k]*bf2f(h4[k].z);
                acc[3] += pk[k]*bf2f(h4[k].w);
            }
        } else {
            uint32 h2v[4];
            #pragma unroll
            for (int k = 0; k < 4; k++) h2v[k] = *(const uint32*)(hbase + (size_t)(uint32)sk[k]*RB);
            #pragma unroll
            for (int k = 0; k < 4; k++){
                acc[0] += pk[k]*bf2f((unsigned short)(h2v[k] & 0xffff));
                acc[1] += pk[k]*bf2f((unsigned short)(h2v[k] >> 16));
            }
        }
    }

    float inv = 1.f/(den[(uint32)n*H + head] + 1e-16f);
    if constexpr (LAYER == 1){
        unsigned short o[CPL];
        #pragma unroll
        for (int j = 0; j < CPL; j++){
            float r = acc[j]*inv + bias[c0 + j];
            r = (r > 0.f) ? r : (__expf(r) - 1.f);   // elu
            o[j] = f2bf(r);
        }
        if constexpr (CPL == 4){
            ushort4 ov; ov.x = o[0]; ov.y = o[1]; ov.z = o[2]; ov.w = o[3];
            *(ushort4*)&out_bf[(size_t)n*C + c0] = ov;
        }
    } else {
        float o[CPL];
        #pragma unroll
        for (int j = 0; j < CPL; j++){
            float r = acc[j]*inv + bias[c0 + j];
            r = (r > 0.f) ? r : (__expf(r) - 1.f);   // elu
            o[j] = r*gate[(c0 + j) & 63];
        }
        if constexpr (CPL == 2){
            *(float2*)&out_f[(size_t)n*C + c0] = make_float2(o[0], o[1]);
        }
    }
}

// ---------------- attn MLP via MFMA ----------------
__global__ __launch_bounds__(256) void k_attn_mfma(const float* __restrict__ outh,
        const unsigned short* __restrict__ Wfa, const float* __restrict__ ab1,
        const float* __restrict__ aw2, const float* __restrict__ ab2,
        float* __restrict__ attn, int N)
{
    __shared__ unsigned short Af[4*8*64*8];   // 32 KB
    const int tid = threadIdx.x;
    const int l   = tid & 63;
    const int w   = tid >> 6;
    const int n0  = blockIdx.x * 128;

    const int r  = tid >> 1;
    const int kh = tid & 1;
    const int rt8 = r >> 4, rr = r & 15;
    int crow = n0 + r; if (crow > N-1) crow = N-1;
    const float* src = outh + (size_t)crow*C2 + kh*16;
    #pragma unroll
    for (int s = 0; s < 4; s++){
        float4 a = *(const float4*)(src + s*32 + 0);
        float4 b = *(const float4*)(src + s*32 + 4);
        float4 c = *(const float4*)(src + s*32 + 8);
        float4 d = *(const float4*)(src + s*32 + 12);
        uint4 u0, u1;
        u0.x = pack2(a.x, a.y); u0.y = pack2(a.z, a.w);
        u0.z = pack2(b.x, b.y); u0.w = pack2(b.z, b.w);
        u1.x = pack2(c.x, c.y); u1.y = pack2(c.z, c.w);
        u1.z = pack2(d.x, d.y); u1.w = pack2(d.z, d.w);
        int d0 = ((s*8 + rt8)*64 + (kh*2)*16 + rr)*8;
        *(uint4*)&Af[d0]       = u0;
        *(uint4*)&Af[d0 + 128] = u1;
    }
    __syncthreads();

    f32x4 acc[4][2];
    #pragma unroll
    for (int i = 0; i < 4; i++)
        #pragma unroll
        for (int rt = 0; rt < 2; rt++)
            acc[i][rt] = (f32x4){0.f, 0.f, 0.f, 0.f};

    #pragma unroll
    for (int s = 0; s < 4; s++){
        bf16x8 af[2];
        #pragma unroll
        for (int rt = 0; rt < 2; rt++)
            af[rt] = __builtin_bit_cast(bf16x8, *(const uint4*)&Af[((s*8 + w*2 + rt)*64 + l)*8]);
        #pragma unroll
        for (int i = 0; i < 4; i++){
            bf16x8 bw = __builtin_bit_cast(bf16x8, *(const uint4*)&Wfa[((size_t)(s*4 + i)*64 + l)*8]);
            #pragma unroll
            for (int rt = 0; rt < 2; rt++)
                acc[i][rt] = __builtin_amdgcn_mfma_f32_16x16x32_bf16(bw, af[rt], acc[i][rt], 0, 0, 0);
        }
    }

    const int g = l >> 4;
    float4 abv[4], awv[4];
    #pragma unroll
    for (int i = 0; i < 4; i++){
        abv[i] = *(const float4*)&ab1[i*16 + g*4];
        awv[i] = *(const float4*)&aw2[i*16 + g*4];
    }
    float b2v = ab2[0];
    #pragma unroll
    for (int rt = 0; rt < 2; rt++){
        int node = n0 + (w*2 + rt)*16 + (l & 15);
        float part = 0.f;
        #pragma unroll
        for (int i = 0; i < 4; i++){
            float v0 = fmaxf(acc[i][rt][0] + abv[i].x, 0.f);
            float v1 = fmaxf(acc[i][rt][1] + abv[i].y, 0.f);
            float v2 = fmaxf(acc[i][rt][2] + abv[i].z, 0.f);
            float v3 = fmaxf(acc[i][rt][3] + abv[i].w, 0.f);
            part += v0*awv[i].x + v1*awv[i].y + v2*awv[i].z + v3*awv[i].w;
        }
        part += __shfl_xor(part, 16, 64);
        part += __shfl_xor(part, 32, 64);
        if (g == 0 && node < N)
            attn[node] = 1.f/(1.f + __expf(-(part + b2v)));
    }
}

extern "C" void kernel_launch(void* const* d_in, const int* in_sizes, int n_in,
                              void* d_out, int out_size, void* d_ws, size_t ws_size,
                              hipStream_t stream)
{
    const float* x    = (const float*)d_in[0];
    const int*   ei   = (const int*)  d_in[1];
    const float* pad  = (const float*)d_in[2];
    const float* W1   = (const float*)d_in[3];
    const float* as1  = (const float*)d_in[4];
    const float* ad1  = (const float*)d_in[5];
    const float* b1   = (const float*)d_in[6];
    const float* W2   = (const float*)d_in[7];
    const float* as2  = (const float*)d_in[8];
    const float* ad2  = (const float*)d_in[9];
    const float* b2   = (const float*)d_in[10];
    const float* aw1  = (const float*)d_in[11];
    const float* ab1  = (const float*)d_in[12];
    const float* aw2  = (const float*)d_in[13];
    const float* ab2  = (const float*)d_in[14];
    const float* gw   = (const float*)d_in[15];
    const float* gb   = (const float*)d_in[16];

    const int N = in_sizes[0] / IN_DIM;
    const int E = in_sizes[1] / 2;

    float* outh    = (float*)d_out;
    float* outattn = outh + (size_t)N*C2;

    char* w = (char*)d_ws;
    auto alloc = [&](size_t bytes)->char*{
        char* p = w;
        w += (bytes + 255) & ~(size_t)255;
        return p;
    };
    unsigned short* h1  = (unsigned short*)alloc((size_t)N*C1*2);
    unsigned short* x2  = (unsigned short*)alloc((size_t)N*C1*2);
    unsigned short* h2  = (unsigned short*)alloc((size_t)N*C2*2);
    float* als1 = (float*)alloc((size_t)N*4*4);
    float* ald1 = (float*)alloc((size_t)N*4*4);
    float* als2 = (float*)alloc((size_t)N*2*4);
    float* ald2 = (float*)alloc((size_t)N*2*4);
    int* deg    = (int*)alloc((size_t)N*4);
    int* cur    = (int*)alloc((size_t)N*4);
    int* rowptr = (int*)alloc((size_t)(N+1)*4);
    int* colx   = (int*)alloc((size_t)E*4);
    int* dstx   = (int*)alloc((size_t)E*4);
    int* part   = (int*)alloc(512*4);
    unsigned short* Wf1 = (unsigned short*)alloc((size_t)12*16*64*8*2);
    unsigned short* Wf2 = (unsigned short*)alloc((size_t)8*8*64*8*2);
    unsigned short* Wfa = (unsigned short*)alloc((size_t)4*4*64*8*2);
    float* c1v  = (float*)alloc(C1*4);
    float* gate = (float*)alloc(HID*4);

    // Lifetime-based aliases (no new footprint):
    float* ep1    = (float*)h2;                                   // E*4 floats
    float* den1   = (float*)((char*)h2 + (size_t)E*16);           // N*4 floats
    float* pSelf1 = (float*)((char*)h2 + (size_t)E*16 + (size_t)N*16);
    float* ep2    = (float*)x2;                                   // E*2 floats
    float* den2   = (float*)((char*)x2 + (size_t)E*8);            // N*2 floats
    float* pSelf2 = (float*)((char*)x2 + (size_t)E*8 + (size_t)N*8);

    const int nbN = (N + 255)/256;
    const int nbE = (E + 255)/256;
    const int nbW = (N + 3)/4;        // wave-per-node kernels
    const int nbG1 = (N + 31)/32;     // gemm1 row blocks (32-row tiles)
    const int nbG2 = (N + 63)/64;     // gemm2 row blocks
    const int nbA = (N + 127)/128;    // attn-MLP row blocks

    // weight swizzles + constants (independent of CSR)
    k_cvtW <<<(192+3)/4, 256, 0, stream>>>(W1, Wf1, C1, 16, 192);
    k_cvtW <<<(64+3)/4,  256, 0, stream>>>(W2, Wf2, C2, 8, 64);
    k_cvtW <<<(16+3)/4,  256, 0, stream>>>(aw1, Wfa, HID, 4, 16);
    k_prep <<<1, 256, 0, stream>>>(W1, pad, gw, gb, c1v, gate);

    // CSR by destination (round-9 scan form)
    k_zero   <<<nbN, 256, 0, stream>>>(deg, cur, N);
    k_hist   <<<nbE, 256, 0, stream>>>(ei, deg, E);
    k_scan1  <<<nbN, 256, 0, stream>>>(deg, rowptr, part, N);
    k_scan2  <<<1, 512, 0, stream>>>(part, nbN);
    k_scan3  <<<nbN, 256, 0, stream>>>(rowptr, part, N, E);
    k_scatter<<<nbE, 256, 0, stream>>>(ei, rowptr, cur, colx, dstx, E);

    // ---- layer 1 ----
    k_gemm1_mfma<<<nbG1, 256, 0, stream>>>(x, Wf1, c1v, as1, ad1, h1, als1, ald1, N);
    k_elogit<4><<<nbE, 256, 0, stream>>>(colx, dstx, als1, ald1, ep1, E);
    k_segsm<4> <<<(N*4 + 255)/256, 256, 0, stream>>>(rowptr, als1, ald1, ep1, den1, pSelf1, N*4);
    k_gat<4,4,1><<<nbW, 256, 0, stream>>>(h1, ep1, den1, pSelf1, rowptr, colx, b1,
                                          nullptr, x2, nullptr, N);

    // ---- layer 2 ----
    k_gemm2_mfma<<<nbG2, 256, 0, stream>>>(x2, Wf2, as2, ad2, h2, als2, ald2, N);
    k_elogit<2><<<nbE, 256, 0, stream>>>(colx, dstx, als2, ald2, ep2, E);
    k_segsm<2> <<<(N*2 + 255)/256, 256, 0, stream>>>(rowptr, als2, ald2, ep2, den2, pSelf2, N*2);
    k_gat<2,2,2><<<nbW, 256, 0, stream>>>(h2, ep2, den2, pSelf2, rowptr, colx, b2,
                                          gate, nullptr, outh, N);

    // ---- attention-score MLP (MFMA) ----
    k_attn_mfma<<<nbA, 256, 0, stream>>>(outh, Wfa, ab1, aw2, ab2, outattn, N);
}